// Round 7
// baseline (1958.276 us; speedup 1.0000x reference)
//
#include <hip/hip_runtime.h>
#include <hip/hip_bf16.h>

#define NN 100000
#define NE 1600000
#define DD 64
#define NG 256
#define SHIFT 6     // 64 nodes per bucket
#define NBK 1563    // ceil(NN/64)
#define CHUNK 6250  // edges per scatter block (256 blocks)

typedef __attribute__((ext_vector_type(8))) short bf16x8;
typedef __attribute__((ext_vector_type(4))) float f32x4;

__device__ __forceinline__ float b2f(ushort u){
  unsigned v = ((unsigned)u) << 16;
  return __uint_as_float(v);
}
__device__ __forceinline__ ushort f2b(float f){
  __hip_bfloat16 b = __float2bfloat16(f);
  return *(ushort*)&b;
}

// ---------------- bucketed edge grouping (dst-local, packed 4B) ----------------
__global__ void k_bhist(const int* __restrict__ dst, int* __restrict__ bcnt){
  __shared__ int h[NBK];
  for (int i=threadIdx.x; i<NBK; i+=256) h[i]=0;
  __syncthreads();
  const int stride = 256*256;
  for (int e = blockIdx.x*256 + threadIdx.x; e < NE; e += stride)
    atomicAdd(&h[dst[e]>>SHIFT], 1);
  __syncthreads();
  for (int i=threadIdx.x; i<NBK; i+=256) if (h[i]) atomicAdd(&bcnt[i], h[i]);
}

// single-block multi-chunk exclusive scan over NBK buckets
__global__ void k_bscan(const int* __restrict__ bcnt, int* __restrict__ gbase, int* __restrict__ gcur){
  __shared__ int s[512];
  __shared__ int carry;
  int t = threadIdx.x;
  if (t == 0) carry = 0;
  __syncthreads();
  for (int c0 = 0; c0 < NBK; c0 += 512){
    int i = c0 + t;
    int v = (i < NBK) ? bcnt[i] : 0;
    s[t] = v;
    __syncthreads();
    for (int off=1; off<512; off<<=1){
      int u = (t >= off) ? s[t-off] : 0;
      __syncthreads();
      s[t] += u;
      __syncthreads();
    }
    int excl = s[t] - v + carry;
    if (i < NBK){ gbase[i] = excl; gcur[i] = excl; }
    __syncthreads();
    if (t == 511) carry += s[511];
    __syncthreads();
  }
}

__global__ __launch_bounds__(256) void k_bscatter(const int* __restrict__ src, const int* __restrict__ dst,
                           int* __restrict__ gcur, unsigned* __restrict__ ebuf){
  __shared__ int h[NBK];
  __shared__ int base[NBK];
  __shared__ int lcur[NBK];
  for (int i=threadIdx.x; i<NBK; i+=256) h[i]=0;
  __syncthreads();
  const int e0 = blockIdx.x*CHUNK;
  const int e1 = min(e0+CHUNK, NE);
  for (int e=e0+threadIdx.x; e<e1; e+=256) atomicAdd(&h[dst[e]>>SHIFT], 1);
  __syncthreads();
  for (int i=threadIdx.x; i<NBK; i+=256){
    base[i] = h[i] ? atomicAdd(&gcur[i], h[i]) : 0;
    lcur[i] = 0;
  }
  __syncthreads();
  for (int e=e0+threadIdx.x; e<e1; e+=256){
    int d = dst[e];
    int b = d >> SHIFT;
    int r = atomicAdd(&lcur[b], 1);
    ebuf[base[b]+r] = ((unsigned)(d & 63) << 17) | (unsigned)src[e];
  }
}

// ---------------- one-time casts / weight packing ----------------
__global__ void k_cast(const float* __restrict__ x, ushort* __restrict__ xb){
  int i = blockIdx.x*256 + threadIdx.x;
  if (i*4 < NN*DD){
    float4 v = *(const float4*)&x[i*4];
    ushort4 o;
    o.x = f2b(v.x); o.y = f2b(v.y); o.z = f2b(v.z); o.w = f2b(v.w);
    *(ushort4*)&xb[i*4] = o;
  }
}

// wp layout per layer: [s(2)][t(8)][lane(64)][j(8)] bf16
// value = W[k][col], k = s*32 + (lane>>4)*8 + j, col = t*16 + (lane&15)
__global__ void k_wpack3(const float* __restrict__ Wr1, const float* __restrict__ Wo1,
                         const float* __restrict__ Wr2, const float* __restrict__ Wo2,
                         const float* __restrict__ Wr3, const float* __restrict__ Wo3,
                         ushort* __restrict__ wp){
  int i = blockIdx.x*256 + threadIdx.x;
  if (i >= 3*8192) return;
  int lay = i >> 13;
  int r = i & 8191;
  int j = r & 7, l = (r>>3) & 63, t = (r>>9) & 7, s = r >> 12;
  int k = s*32 + ((l>>4)<<3) + j;
  int col = t*16 + (l&15);
  const float* Wrel  = (lay==0) ? Wr1 : (lay==1) ? Wr2 : Wr3;
  const float* Wroot = (lay==0) ? Wo1 : (lay==1) ? Wo2 : Wo3;
  float v = (col < 64) ? Wrel[k*64 + col] : Wroot[k*64 + (col-64)];
  wp[i] = f2b(v);
}

// ---------------- MFMA dual GEMM: [Y | R] = A @ [Wrel | Wroot] ----------------
__global__ __launch_bounds__(256) void k_gemm_mfma(const ushort* __restrict__ A,
    const ushort* __restrict__ wp, ushort* __restrict__ Y, ushort* __restrict__ Rr){
  const int w = threadIdx.x >> 6, l = threadIdx.x & 63;
  const int m = l & 15, kg = l >> 4;
  const int row0 = blockIdx.x*64 + w*16;
  int arow = row0 + m; if (arow >= NN) arow = NN-1;   // clamp; stores are guarded
  bf16x8 a0 = *(const bf16x8*)&A[(size_t)arow*64 + kg*8];
  bf16x8 a1 = *(const bf16x8*)&A[(size_t)arow*64 + 32 + kg*8];
  f32x4 acc[8];
  #pragma unroll
  for (int t=0; t<8; t++){
    bf16x8 b0 = *(const bf16x8*)&wp[((size_t)(0*8+t)*64 + l)*8];
    bf16x8 b1 = *(const bf16x8*)&wp[((size_t)(1*8+t)*64 + l)*8];
    f32x4 c = {0.f, 0.f, 0.f, 0.f};
    c = __builtin_amdgcn_mfma_f32_16x16x32_bf16(a0, b0, c, 0, 0, 0);
    c = __builtin_amdgcn_mfma_f32_16x16x32_bf16(a1, b1, c, 0, 0, 0);
    acc[t] = c;
  }
  #pragma unroll
  for (int t=0; t<8; t++){
    #pragma unroll
    for (int reg=0; reg<4; reg++){
      int row = row0 + kg*4 + reg;       // D: row = (lane>>4)*4 + reg, col = lane&15
      if (row < NN){
        ushort o = f2b(acc[t][reg]);
        if (t < 4) Y [(size_t)row*64 + t*16 + m]     = o;
        else       Rr[(size_t)row*64 + (t-4)*16 + m] = o;
      }
    }
  }
}

// ---------------- LDS-bucket aggregation: block = 64-node bucket ----------------
// h[node] = act( sum_{e->node} Y[src_e] + R[node] + brel )
__global__ __launch_bounds__(256) void k_aggr_lds(
    const unsigned* __restrict__ ebuf, const int* __restrict__ gbase, const int* __restrict__ bcnt,
    const ushort* __restrict__ Y, const ushort* __restrict__ R,
    const float* __restrict__ brel, ushort* __restrict__ h, int do_relu){
  __shared__ float acc[64*65];     // padded row: bank spread for ds_add
  __shared__ unsigned se[512];
  const int tid = threadIdx.x;
  const int b = blockIdx.x;
  for (int i=tid; i<64*65; i+=256) acc[i]=0.f;
  const int beg = gbase[b], cnt = bcnt[b];
  __syncthreads();
  const int q = tid & 15;          // column quarter: cols 4q..4q+3
  const int eg = tid >> 4;         // 16 concurrent edge slots
  for (int t0=0; t0<cnt; t0+=512){
    int n = min(512, cnt-t0);
    for (int i=tid; i<n; i+=256) se[i] = ebuf[beg+t0+i];
    __syncthreads();
    #pragma unroll 4
    for (int e=eg; e<n; e+=16){
      unsigned p = se[e];
      int srcn = (int)(p & 0x1FFFFu);
      int dl   = (int)(p >> 17);
      ushort4 y4 = *(const ushort4*)&Y[(size_t)srcn*64 + q*4];
      float* ap = &acc[dl*65 + q*4];
      atomicAdd(&ap[0], b2f(y4.x));
      atomicAdd(&ap[1], b2f(y4.y));
      atomicAdd(&ap[2], b2f(y4.z));
      atomicAdd(&ap[3], b2f(y4.w));
    }
    __syncthreads();
  }
  const int node0 = b << 6;
  for (int i=tid; i<4096; i+=256){
    int nl = i>>6, c = i&63;
    int node = node0 + nl;
    if (node < NN){
      float v = acc[nl*65 + c] + b2f(R[(size_t)node*64 + c]) + brel[c];
      if (do_relu) v = fmaxf(v, 0.f);
      h[(size_t)node*64 + c] = f2b(v);
    }
  }
}

// ---------------- pooling ----------------
__global__ void k_ranges(const int* __restrict__ batch, int* __restrict__ gstart, int* __restrict__ gend){
  int g = blockIdx.x*blockDim.x + threadIdx.x;
  if (g >= NG) return;
  int lo=0, hi=NN;
  while (lo<hi){ int mid=(lo+hi)>>1; if (batch[mid] < g) lo=mid+1; else hi=mid; }
  int s = lo;
  lo=0; hi=NN;
  while (lo<hi){ int mid=(lo+hi)>>1; if (batch[mid] < g+1) lo=mid+1; else hi=mid; }
  gstart[g]=s; gend[g]=lo;
}

__global__ void k_pool(const ushort* __restrict__ h, const int* __restrict__ gstart,
                       const int* __restrict__ gend, float* __restrict__ pooled){
  int g = blockIdx.x;
  int lane = threadIdx.x & 63;
  int w = threadIdx.x >> 6;
  int beg = gstart[g], end = gend[g];
  float acc = 0.f;
  for (int n = beg + w; n < end; n += 4) acc += b2f(h[(size_t)n*64 + lane]);
  __shared__ float red[4][64];
  red[w][lane] = acc;
  __syncthreads();
  if (w == 0){
    float v = red[0][lane]+red[1][lane]+red[2][lane]+red[3][lane];
    int cnt = end - beg;
    pooled[g*64+lane] = v / fmaxf((float)cnt, 1.f);
  }
}

__global__ void k_final(const float* __restrict__ pooled, const float* __restrict__ Wlin,
                        const float* __restrict__ blin, float* __restrict__ out){
  __shared__ float sW[64*64];
  __shared__ float sP[4*64];
  int tid = threadIdx.x;
  for (int i=tid; i<4096; i+=256) sW[i] = Wlin[i];
  int g0 = blockIdx.x*4;
  { int g = g0 + tid/64; sP[tid] = (g<NG) ? pooled[g*64 + (tid&63)] : 0.f; }
  __syncthreads();
  int j = tid & 63, gl = tid >> 6;
  int g = g0 + gl;
  float acc = blin[j];
  for (int k=0;k<64;k++) acc += sP[gl*64+k]*sW[k*64+j];
  if (g < NG) out[g*64+j] = acc;
}

extern "C" void kernel_launch(void* const* d_in, const int* in_sizes, int n_in,
                              void* d_out, int out_size, void* d_ws, size_t ws_size,
                              hipStream_t stream){
  const float* x     = (const float*)d_in[0];
  const int*   ei    = (const int*)  d_in[1];
  const int*   batch = (const int*)  d_in[2];
  const float* Wrel1 = (const float*)d_in[3];
  const float* brel1 = (const float*)d_in[4];
  const float* Wroot1= (const float*)d_in[5];
  const float* Wrel2 = (const float*)d_in[6];
  const float* brel2 = (const float*)d_in[7];
  const float* Wroot2= (const float*)d_in[8];
  const float* Wrel3 = (const float*)d_in[9];
  const float* brel3 = (const float*)d_in[10];
  const float* Wroot3= (const float*)d_in[11];
  const float* Wlin  = (const float*)d_in[12];
  const float* blin  = (const float*)d_in[13];
  const int* src = ei;
  const int* dst = ei + NE;

  char* wsB = (char*)d_ws;
  size_t off = 0;
  auto alloc = [&](size_t bytes)->void*{
    void* p = wsB + off; off = (off + bytes + 255) & ~(size_t)255; return p;
  };
  int*      bcnt   = (int*)     alloc(NBK*4);
  int*      gbase  = (int*)     alloc(NBK*4);
  int*      gcur   = (int*)     alloc(NBK*4);
  unsigned* ebuf   = (unsigned*)alloc((size_t)NE*4);      // 6.4 MB packed (dl<<17|src)
  ushort*   xb     = (ushort*)  alloc((size_t)NN*64*2);   // 12.8 MB
  ushort*   wp     = (ushort*)  alloc((size_t)3*8192*2);  // 48 KB
  ushort*   Y      = (ushort*)  alloc((size_t)NN*64*2);   // 12.8 MB
  ushort*   R      = (ushort*)  alloc((size_t)NN*64*2);   // 12.8 MB
  ushort*   h1     = (ushort*)  alloc((size_t)NN*64*2);   // 12.8 MB
  ushort*   h2     = (ushort*)  alloc((size_t)NN*64*2);   // 12.8 MB
  int*      gstart = (int*)     alloc(NG*4);
  int*      gend   = (int*)     alloc(NG*4);
  float*    pooled = (float*)   alloc(NG*64*4);

  hipMemsetAsync(bcnt, 0, NBK*4, stream);

  k_cast    <<<(NN*DD/4+255)/256,256,0,stream>>>(x, xb);
  k_wpack3  <<<(3*8192+255)/256,256,0,stream>>>(Wrel1,Wroot1,Wrel2,Wroot2,Wrel3,Wroot3, wp);
  k_bhist   <<<256,256,0,stream>>>(dst, bcnt);
  k_bscan   <<<1,512,0,stream>>>(bcnt, gbase, gcur);
  k_bscatter<<<256,256,0,stream>>>(src, dst, gcur, ebuf);

  int gb = (NN+63)/64;

  // layer 1
  k_gemm_mfma<<<gb,256,0,stream>>>(xb, wp + 0*8192, Y, R);
  k_aggr_lds <<<NBK,256,0,stream>>>(ebuf, gbase, bcnt, Y, R, brel1, h1, 1);
  // layer 2
  k_gemm_mfma<<<gb,256,0,stream>>>(h1, wp + 1*8192, Y, R);
  k_aggr_lds <<<NBK,256,0,stream>>>(ebuf, gbase, bcnt, Y, R, brel2, h2, 1);
  // layer 3 (no relu)
  k_gemm_mfma<<<gb,256,0,stream>>>(h2, wp + 2*8192, Y, R);
  k_aggr_lds <<<NBK,256,0,stream>>>(ebuf, gbase, bcnt, Y, R, brel3, h1, 0);

  k_ranges<<<1,256,0,stream>>>(batch, gstart, gend);
  k_pool  <<<NG,256,0,stream>>>(h1, gstart, gend, pooled);
  k_final <<<NG/4,256,0,stream>>>(pooled, Wlin, blin, (float*)d_out);
}

// Round 8
// 324.855 us; speedup vs baseline: 6.0282x; 6.0282x over previous
//
#include <hip/hip_runtime.h>
#include <hip/hip_bf16.h>

#define NN 100000
#define NE 1600000
#define DD 64
#define NG 256
#define CAP 64     // padded CSR slots/node; Poisson(16): P(any deg>64) ~ 2e-13
#define SHIFT 8    // 256 nodes per bucket
#define NBK 391    // ceil(NN/256)
#define CHUNK 6250 // edges per scatter block (256 blocks)

typedef __attribute__((ext_vector_type(8))) short bf16x8;
typedef __attribute__((ext_vector_type(4))) float f32x4;

__device__ __forceinline__ float b2f(ushort u){
  unsigned v = ((unsigned)u) << 16;
  return __uint_as_float(v);
}
__device__ __forceinline__ ushort f2b(float f){
  __hip_bfloat16 b = __float2bfloat16(f);
  return *(ushort*)&b;
}

// ---------------- bucketed edge grouping (dst-local, packed 4B) ----------------
__global__ void k_bhist(const int* __restrict__ dst, int* __restrict__ bcnt){
  __shared__ int h[NBK];
  for (int i=threadIdx.x; i<NBK; i+=256) h[i]=0;
  __syncthreads();
  const int stride = 256*256;
  for (int e = blockIdx.x*256 + threadIdx.x; e < NE; e += stride)
    atomicAdd(&h[dst[e]>>SHIFT], 1);
  __syncthreads();
  for (int i=threadIdx.x; i<NBK; i+=256) if (h[i]) atomicAdd(&bcnt[i], h[i]);
}

__global__ void k_bscan(const int* __restrict__ bcnt, int* __restrict__ gbase, int* __restrict__ gcur){
  __shared__ int s[512];
  int t = threadIdx.x;
  int v = (t < NBK) ? bcnt[t] : 0;
  s[t] = v;
  __syncthreads();
  for (int off=1; off<512; off<<=1){
    int u = (t >= off) ? s[t-off] : 0;
    __syncthreads();
    s[t] += u;
    __syncthreads();
  }
  if (t < NBK){ int b = s[t] - v; gbase[t] = b; gcur[t] = b; }
}

__global__ __launch_bounds__(256) void k_bscatter(const int* __restrict__ src, const int* __restrict__ dst,
                           int* __restrict__ gcur, unsigned* __restrict__ ebuf){
  __shared__ int h[NBK];
  __shared__ int base[NBK];
  __shared__ int lcur[NBK];
  for (int i=threadIdx.x; i<NBK; i+=256) h[i]=0;
  __syncthreads();
  const int e0 = blockIdx.x*CHUNK;
  const int e1 = min(e0+CHUNK, NE);
  for (int e=e0+threadIdx.x; e<e1; e+=256) atomicAdd(&h[dst[e]>>SHIFT], 1);
  __syncthreads();
  for (int i=threadIdx.x; i<NBK; i+=256){
    base[i] = h[i] ? atomicAdd(&gcur[i], h[i]) : 0;
    lcur[i] = 0;
  }
  __syncthreads();
  for (int e=e0+threadIdx.x; e<e1; e+=256){
    int d = dst[e];
    int b = d >> SHIFT;
    int r = atomicAdd(&lcur[b], 1);
    ebuf[base[b]+r] = ((unsigned)(d & 255) << 17) | (unsigned)src[e];   // 8b local-dst | 17b src
  }
}

// per-bucket blocks: node id reconstructed from blockIdx; 64KB csrp window -> L2-local writes
__global__ void k_bfill(const unsigned* __restrict__ ebuf, const int* __restrict__ gbase,
                        const int* __restrict__ bcnt, int* __restrict__ deg, int* __restrict__ csrp){
  int b = blockIdx.x;
  int beg = gbase[b], cnt = bcnt[b];
  for (int i = threadIdx.x; i < cnt; i += 256){
    unsigned p = ebuf[beg+i];
    int d = (b << SHIFT) | (int)(p >> 17);
    int q = atomicAdd(&deg[d], 1);
    if (q < CAP) csrp[(size_t)d*CAP + q] = (int)(p & 0x1FFFFu);
  }
}

// ---------------- weight packing ----------------
// wp layout per layer: [s(2)][t(8)][lane(64)][j(8)] bf16
// value = W[k][col], k = s*32 + (lane>>4)*8 + j, col = t*16 + (lane&15)
__global__ void k_wpack3(const float* __restrict__ Wr1, const float* __restrict__ Wo1,
                         const float* __restrict__ Wr2, const float* __restrict__ Wo2,
                         const float* __restrict__ Wr3, const float* __restrict__ Wo3,
                         ushort* __restrict__ wp){
  int i = blockIdx.x*256 + threadIdx.x;
  if (i >= 3*8192) return;
  int lay = i >> 13;
  int r = i & 8191;
  int j = r & 7, l = (r>>3) & 63, t = (r>>9) & 7, s = r >> 12;
  int k = s*32 + ((l>>4)<<3) + j;
  int col = t*16 + (l&15);
  const float* Wrel  = (lay==0) ? Wr1 : (lay==1) ? Wr2 : Wr3;
  const float* Wroot = (lay==0) ? Wo1 : (lay==1) ? Wo2 : Wo3;
  float v = (col < 64) ? Wrel[k*64 + col] : Wroot[k*64 + (col-64)];
  wp[i] = f2b(v);
}

// ---------------- MFMA dual GEMM: [Y | R] = A @ [Wrel | Wroot] ----------------
// A: f32 [NN][64] (aIsF32=1, layer 1) or bf16 [NN][64]. No LDS, no barriers.
__global__ __launch_bounds__(256) void k_gemm_mfma(const void* __restrict__ Av, int aIsF32,
    const ushort* __restrict__ wp, ushort* __restrict__ Y, ushort* __restrict__ Rr){
  const int w = threadIdx.x >> 6, l = threadIdx.x & 63;
  const int m = l & 15, kg = l >> 4;
  const int row0 = blockIdx.x*64 + w*16;
  int arow = row0 + m; if (arow >= NN) arow = NN-1;   // clamp; stores are guarded
  bf16x8 a0, a1;
  if (aIsF32){
    const float* Af = (const float*)Av;
    float4 f0 = *(const float4*)&Af[(size_t)arow*64 + kg*8];
    float4 f1 = *(const float4*)&Af[(size_t)arow*64 + kg*8 + 4];
    float4 f2 = *(const float4*)&Af[(size_t)arow*64 + 32 + kg*8];
    float4 f3 = *(const float4*)&Af[(size_t)arow*64 + 32 + kg*8 + 4];
    a0[0]=(short)f2b(f0.x); a0[1]=(short)f2b(f0.y); a0[2]=(short)f2b(f0.z); a0[3]=(short)f2b(f0.w);
    a0[4]=(short)f2b(f1.x); a0[5]=(short)f2b(f1.y); a0[6]=(short)f2b(f1.z); a0[7]=(short)f2b(f1.w);
    a1[0]=(short)f2b(f2.x); a1[1]=(short)f2b(f2.y); a1[2]=(short)f2b(f2.z); a1[3]=(short)f2b(f2.w);
    a1[4]=(short)f2b(f3.x); a1[5]=(short)f2b(f3.y); a1[6]=(short)f2b(f3.z); a1[7]=(short)f2b(f3.w);
  } else {
    const ushort* Ab = (const ushort*)Av;
    a0 = *(const bf16x8*)&Ab[(size_t)arow*64 + kg*8];
    a1 = *(const bf16x8*)&Ab[(size_t)arow*64 + 32 + kg*8];
  }
  f32x4 acc[8];
  #pragma unroll
  for (int t=0; t<8; t++){
    bf16x8 b0 = *(const bf16x8*)&wp[((size_t)(0*8+t)*64 + l)*8];
    bf16x8 b1 = *(const bf16x8*)&wp[((size_t)(1*8+t)*64 + l)*8];
    f32x4 c = {0.f, 0.f, 0.f, 0.f};
    c = __builtin_amdgcn_mfma_f32_16x16x32_bf16(a0, b0, c, 0, 0, 0);
    c = __builtin_amdgcn_mfma_f32_16x16x32_bf16(a1, b1, c, 0, 0, 0);
    acc[t] = c;
  }
  #pragma unroll
  for (int t=0; t<8; t++){
    #pragma unroll
    for (int reg=0; reg<4; reg++){
      int row = row0 + kg*4 + reg;       // D: row = (lane>>4)*4 + reg, col = lane&15
      if (row < NN){
        ushort o = f2b(acc[t][reg]);
        if (t < 4) Y [(size_t)row*64 + t*16 + m]     = o;
        else       Rr[(size_t)row*64 + (t-4)*16 + m] = o;
      }
    }
  }
}

// ---------------- gather-aggregate: 2 edges/wave-instr, 8 edges in flight ----------------
// lanes 0-31: even edges, lanes 32-63: odd edges; each lane owns col pair (2*(lane&31), +1)
__global__ __launch_bounds__(256) void k_aggr(const ushort* __restrict__ Y,
    const ushort* __restrict__ R, const float* __restrict__ brel,
    const int* __restrict__ deg, const int* __restrict__ csrp,
    ushort* __restrict__ hout, int do_relu){
  int node = blockIdx.x*4 + (threadIdx.x>>6);
  if (node >= NN) return;
  int lane = threadIdx.x & 63;
  int half = lane >> 5;
  int c2 = (lane & 31) << 1;
  int dc = deg[node]; if (dc > CAP) dc = CAP;
  const int* lst = csrp + (size_t)node*CAP;
  float ax = 0.f, ay = 0.f;
  int e = half;
  for (; e+6 < dc; e += 8){               // 4 ushort2 loads in flight x 2 halves = 8 edges
    int s0=lst[e], s1=lst[e+2], s2=lst[e+4], s3=lst[e+6];
    ushort2 y0 = *(const ushort2*)&Y[(size_t)s0*64 + c2];
    ushort2 y1 = *(const ushort2*)&Y[(size_t)s1*64 + c2];
    ushort2 y2 = *(const ushort2*)&Y[(size_t)s2*64 + c2];
    ushort2 y3 = *(const ushort2*)&Y[(size_t)s3*64 + c2];
    ax += b2f(y0.x)+b2f(y1.x)+b2f(y2.x)+b2f(y3.x);
    ay += b2f(y0.y)+b2f(y1.y)+b2f(y2.y)+b2f(y3.y);
  }
  for (; e < dc; e += 2){
    ushort2 y = *(const ushort2*)&Y[(size_t)lst[e]*64 + c2];
    ax += b2f(y.x); ay += b2f(y.y);
  }
  ax += __shfl_xor(ax, 32);
  ay += __shfl_xor(ay, 32);
  if (half == 0){
    ushort2 r2 = *(const ushort2*)&R[(size_t)node*64 + c2];
    float vx = ax + b2f(r2.x) + brel[c2];
    float vy = ay + b2f(r2.y) + brel[c2+1];
    if (do_relu){ vx = fmaxf(vx, 0.f); vy = fmaxf(vy, 0.f); }
    ushort2 o; o.x = f2b(vx); o.y = f2b(vy);
    *(ushort2*)&hout[(size_t)node*64 + c2] = o;
  }
}

// ---------------- pooling ----------------
__global__ void k_ranges(const int* __restrict__ batch, int* __restrict__ gstart, int* __restrict__ gend){
  int g = blockIdx.x*blockDim.x + threadIdx.x;
  if (g >= NG) return;
  int lo=0, hi=NN;
  while (lo<hi){ int mid=(lo+hi)>>1; if (batch[mid] < g) lo=mid+1; else hi=mid; }
  int s = lo;
  lo=0; hi=NN;
  while (lo<hi){ int mid=(lo+hi)>>1; if (batch[mid] < g+1) lo=mid+1; else hi=mid; }
  gstart[g]=s; gend[g]=lo;
}

__global__ void k_pool(const ushort* __restrict__ h, const int* __restrict__ gstart,
                       const int* __restrict__ gend, float* __restrict__ pooled){
  int g = blockIdx.x;
  int lane = threadIdx.x & 63;
  int w = threadIdx.x >> 6;
  int beg = gstart[g], end = gend[g];
  float acc = 0.f;
  for (int n = beg + w; n < end; n += 4) acc += b2f(h[(size_t)n*64 + lane]);
  __shared__ float red[4][64];
  red[w][lane] = acc;
  __syncthreads();
  if (w == 0){
    float v = red[0][lane]+red[1][lane]+red[2][lane]+red[3][lane];
    int cnt = end - beg;
    pooled[g*64+lane] = v / fmaxf((float)cnt, 1.f);
  }
}

__global__ void k_final(const float* __restrict__ pooled, const float* __restrict__ Wlin,
                        const float* __restrict__ blin, float* __restrict__ out){
  __shared__ float sW[64*64];
  __shared__ float sP[4*64];
  int tid = threadIdx.x;
  for (int i=tid; i<4096; i+=256) sW[i] = Wlin[i];
  int g0 = blockIdx.x*4;
  { int g = g0 + tid/64; sP[tid] = (g<NG) ? pooled[g*64 + (tid&63)] : 0.f; }
  __syncthreads();
  int j = tid & 63, gl = tid >> 6;
  int g = g0 + gl;
  float acc = blin[j];
  for (int k=0;k<64;k++) acc += sP[gl*64+k]*sW[k*64+j];
  if (g < NG) out[g*64+j] = acc;
}

extern "C" void kernel_launch(void* const* d_in, const int* in_sizes, int n_in,
                              void* d_out, int out_size, void* d_ws, size_t ws_size,
                              hipStream_t stream){
  const float* x     = (const float*)d_in[0];
  const int*   ei    = (const int*)  d_in[1];
  const int*   batch = (const int*)  d_in[2];
  const float* Wrel1 = (const float*)d_in[3];
  const float* brel1 = (const float*)d_in[4];
  const float* Wroot1= (const float*)d_in[5];
  const float* Wrel2 = (const float*)d_in[6];
  const float* brel2 = (const float*)d_in[7];
  const float* Wroot2= (const float*)d_in[8];
  const float* Wrel3 = (const float*)d_in[9];
  const float* brel3 = (const float*)d_in[10];
  const float* Wroot3= (const float*)d_in[11];
  const float* Wlin  = (const float*)d_in[12];
  const float* blin  = (const float*)d_in[13];
  const int* src = ei;
  const int* dst = ei + NE;

  char* wsB = (char*)d_ws;
  size_t off = 0;
  auto alloc = [&](size_t bytes)->void*{
    void* p = wsB + off; off = (off + bytes + 255) & ~(size_t)255; return p;
  };
  int*      csrp   = (int*)     alloc((size_t)NN*CAP*4);   // 25.6 MB
  int*      deg    = (int*)     alloc((size_t)NN*4);
  int*      bcnt   = (int*)     alloc(NBK*4);
  int*      gbase  = (int*)     alloc(NBK*4);
  int*      gcur   = (int*)     alloc(NBK*4);
  unsigned* ebuf   = (unsigned*)alloc((size_t)NE*4);       // 6.4 MB packed
  ushort*   wp     = (ushort*)  alloc((size_t)3*8192*2);   // 48 KB
  ushort*   Y      = (ushort*)  alloc((size_t)NN*64*2);    // 12.8 MB
  ushort*   R      = (ushort*)  alloc((size_t)NN*64*2);    // 12.8 MB
  ushort*   h1     = (ushort*)  alloc((size_t)NN*64*2);    // 12.8 MB
  ushort*   h2     = (ushort*)  alloc((size_t)NN*64*2);    // 12.8 MB
  int*      gstart = (int*)     alloc(NG*4);
  int*      gend   = (int*)     alloc(NG*4);
  float*    pooled = (float*)   alloc(NG*64*4);

  hipMemsetAsync(deg, 0, (size_t)NN*4, stream);
  hipMemsetAsync(bcnt, 0, NBK*4, stream);

  k_wpack3  <<<(3*8192+255)/256,256,0,stream>>>(Wrel1,Wroot1,Wrel2,Wroot2,Wrel3,Wroot3, wp);
  k_bhist   <<<256,256,0,stream>>>(dst, bcnt);
  k_bscan   <<<1,512,0,stream>>>(bcnt, gbase, gcur);
  k_bscatter<<<256,256,0,stream>>>(src, dst, gcur, ebuf);
  k_bfill   <<<NBK,256,0,stream>>>(ebuf, gbase, bcnt, deg, csrp);

  int gb = (NN+63)/64;
  int ab = (NN+3)/4;

  // layer 1 (A = x, f32, cast fused into GEMM)
  k_gemm_mfma<<<gb,256,0,stream>>>(x,  1, wp + 0*8192, Y, R);
  k_aggr     <<<ab,256,0,stream>>>(Y, R, brel1, deg, csrp, h1, 1);
  // layer 2
  k_gemm_mfma<<<gb,256,0,stream>>>(h1, 0, wp + 1*8192, Y, R);
  k_aggr     <<<ab,256,0,stream>>>(Y, R, brel2, deg, csrp, h2, 1);
  // layer 3 (no relu)
  k_gemm_mfma<<<gb,256,0,stream>>>(h2, 0, wp + 2*8192, Y, R);
  k_aggr     <<<ab,256,0,stream>>>(Y, R, brel3, deg, csrp, h1, 0);

  k_ranges<<<1,256,0,stream>>>(batch, gstart, gend);
  k_pool  <<<NG,256,0,stream>>>(h1, gstart, gend, pooled);
  k_final <<<NG/4,256,0,stream>>>(pooled, Wlin, blin, (float*)d_out);
}

// Round 9
// 299.624 us; speedup vs baseline: 6.5358x; 1.0842x over previous
//
#include <hip/hip_runtime.h>
#include <hip/hip_bf16.h>

#define NN 100000
#define NE 1600000
#define DD 64
#define NG 256
#define CAP 64     // padded CSR slots/node; Poisson(16): P(any deg>64) ~ 2e-13
#define SHIFT 8    // 256 nodes per bucket
#define NBK 391    // ceil(NN/256)
#define CHUNK 6250 // edges per scatter block (256 blocks)

typedef __attribute__((ext_vector_type(8))) short bf16x8;
typedef __attribute__((ext_vector_type(4))) float f32x4;
typedef __attribute__((ext_vector_type(8))) unsigned short ushort8v;

__device__ __forceinline__ float b2f(ushort u){
  unsigned v = ((unsigned)u) << 16;
  return __uint_as_float(v);
}
__device__ __forceinline__ ushort f2b(float f){
  __hip_bfloat16 b = __float2bfloat16(f);
  return *(ushort*)&b;
}

// ---------------- bucketed edge grouping (dst-local, packed 4B) ----------------
__global__ void k_bhist(const int* __restrict__ dst, int* __restrict__ bcnt){
  __shared__ int h[NBK];
  for (int i=threadIdx.x; i<NBK; i+=256) h[i]=0;
  __syncthreads();
  const int stride = 256*256;
  for (int e = blockIdx.x*256 + threadIdx.x; e < NE; e += stride)
    atomicAdd(&h[dst[e]>>SHIFT], 1);
  __syncthreads();
  for (int i=threadIdx.x; i<NBK; i+=256) if (h[i]) atomicAdd(&bcnt[i], h[i]);
}

__global__ void k_bscan(const int* __restrict__ bcnt, int* __restrict__ gbase, int* __restrict__ gcur){
  __shared__ int s[512];
  int t = threadIdx.x;
  int v = (t < NBK) ? bcnt[t] : 0;
  s[t] = v;
  __syncthreads();
  for (int off=1; off<512; off<<=1){
    int u = (t >= off) ? s[t-off] : 0;
    __syncthreads();
    s[t] += u;
    __syncthreads();
  }
  if (t < NBK){ int b = s[t] - v; gbase[t] = b; gcur[t] = b; }
}

__global__ __launch_bounds__(256) void k_bscatter(const int* __restrict__ src, const int* __restrict__ dst,
                           int* __restrict__ gcur, unsigned* __restrict__ ebuf){
  __shared__ int h[NBK];
  __shared__ int base[NBK];
  __shared__ int lcur[NBK];
  for (int i=threadIdx.x; i<NBK; i+=256) h[i]=0;
  __syncthreads();
  const int e0 = blockIdx.x*CHUNK;
  const int e1 = min(e0+CHUNK, NE);
  for (int e=e0+threadIdx.x; e<e1; e+=256) atomicAdd(&h[dst[e]>>SHIFT], 1);
  __syncthreads();
  for (int i=threadIdx.x; i<NBK; i+=256){
    base[i] = h[i] ? atomicAdd(&gcur[i], h[i]) : 0;
    lcur[i] = 0;
  }
  __syncthreads();
  for (int e=e0+threadIdx.x; e<e1; e+=256){
    int d = dst[e];
    int b = d >> SHIFT;
    int r = atomicAdd(&lcur[b], 1);
    ebuf[base[b]+r] = ((unsigned)(d & 255) << 17) | (unsigned)src[e];   // 8b local-dst | 17b src
  }
}

// per-bucket blocks: node id reconstructed from blockIdx; 64KB csrp window -> L2-local writes
__global__ void k_bfill(const unsigned* __restrict__ ebuf, const int* __restrict__ gbase,
                        const int* __restrict__ bcnt, int* __restrict__ deg, int* __restrict__ csrp){
  int b = blockIdx.x;
  int beg = gbase[b], cnt = bcnt[b];
  for (int i = threadIdx.x; i < cnt; i += 256){
    unsigned p = ebuf[beg+i];
    int d = (b << SHIFT) | (int)(p >> 17);
    int q = atomicAdd(&deg[d], 1);
    if (q < CAP) csrp[(size_t)d*CAP + q] = (int)(p & 0x1FFFFu);
  }
}

// ---------------- weight packing ----------------
// wp layout per layer: [s(2)][t(8)][lane(64)][j(8)] bf16
// value = W[k][col], k = s*32 + (lane>>4)*8 + j, col = t*16 + (lane&15)
__global__ void k_wpack3(const float* __restrict__ Wr1, const float* __restrict__ Wo1,
                         const float* __restrict__ Wr2, const float* __restrict__ Wo2,
                         const float* __restrict__ Wr3, const float* __restrict__ Wo3,
                         ushort* __restrict__ wp){
  int i = blockIdx.x*256 + threadIdx.x;
  if (i >= 3*8192) return;
  int lay = i >> 13;
  int r = i & 8191;
  int j = r & 7, l = (r>>3) & 63, t = (r>>9) & 7, s = r >> 12;
  int k = s*32 + ((l>>4)<<3) + j;
  int col = t*16 + (l&15);
  const float* Wrel  = (lay==0) ? Wr1 : (lay==1) ? Wr2 : Wr3;
  const float* Wroot = (lay==0) ? Wo1 : (lay==1) ? Wo2 : Wo3;
  float v = (col < 64) ? Wrel[k*64 + col] : Wroot[k*64 + (col-64)];
  wp[i] = f2b(v);
}

// ---------------- MFMA dual GEMM: [Y | R] = A @ [Wrel | Wroot] ----------------
// A: f32 [NN][64] (aIsF32=1, layer 1) or bf16 [NN][64]. No LDS, no barriers.
__global__ __launch_bounds__(256) void k_gemm_mfma(const void* __restrict__ Av, int aIsF32,
    const ushort* __restrict__ wp, ushort* __restrict__ Y, ushort* __restrict__ Rr){
  const int w = threadIdx.x >> 6, l = threadIdx.x & 63;
  const int m = l & 15, kg = l >> 4;
  const int row0 = blockIdx.x*64 + w*16;
  int arow = row0 + m; if (arow >= NN) arow = NN-1;   // clamp; stores are guarded
  bf16x8 a0, a1;
  if (aIsF32){
    const float* Af = (const float*)Av;
    float4 f0 = *(const float4*)&Af[(size_t)arow*64 + kg*8];
    float4 f1 = *(const float4*)&Af[(size_t)arow*64 + kg*8 + 4];
    float4 f2 = *(const float4*)&Af[(size_t)arow*64 + 32 + kg*8];
    float4 f3 = *(const float4*)&Af[(size_t)arow*64 + 32 + kg*8 + 4];
    a0[0]=(short)f2b(f0.x); a0[1]=(short)f2b(f0.y); a0[2]=(short)f2b(f0.z); a0[3]=(short)f2b(f0.w);
    a0[4]=(short)f2b(f1.x); a0[5]=(short)f2b(f1.y); a0[6]=(short)f2b(f1.z); a0[7]=(short)f2b(f1.w);
    a1[0]=(short)f2b(f2.x); a1[1]=(short)f2b(f2.y); a1[2]=(short)f2b(f2.z); a1[3]=(short)f2b(f2.w);
    a1[4]=(short)f2b(f3.x); a1[5]=(short)f2b(f3.y); a1[6]=(short)f2b(f3.z); a1[7]=(short)f2b(f3.w);
  } else {
    const ushort* Ab = (const ushort*)Av;
    a0 = *(const bf16x8*)&Ab[(size_t)arow*64 + kg*8];
    a1 = *(const bf16x8*)&Ab[(size_t)arow*64 + 32 + kg*8];
  }
  f32x4 acc[8];
  #pragma unroll
  for (int t=0; t<8; t++){
    bf16x8 b0 = *(const bf16x8*)&wp[((size_t)(0*8+t)*64 + l)*8];
    bf16x8 b1 = *(const bf16x8*)&wp[((size_t)(1*8+t)*64 + l)*8];
    f32x4 c = {0.f, 0.f, 0.f, 0.f};
    c = __builtin_amdgcn_mfma_f32_16x16x32_bf16(a0, b0, c, 0, 0, 0);
    c = __builtin_amdgcn_mfma_f32_16x16x32_bf16(a1, b1, c, 0, 0, 0);
    acc[t] = c;
  }
  #pragma unroll
  for (int t=0; t<8; t++){
    #pragma unroll
    for (int reg=0; reg<4; reg++){
      int row = row0 + kg*4 + reg;       // D: row = (lane>>4)*4 + reg, col = lane&15
      if (row < NN){
        ushort o = f2b(acc[t][reg]);
        if (t < 4) Y [(size_t)row*64 + t*16 + m]     = o;
        else       Rr[(size_t)row*64 + (t-4)*16 + m] = o;
      }
    }
  }
}

// ---------------- gather-aggregate: 8 lanes/edge (ushort8), 8 edges/load-instr ----------------
// lane: g = lane>>3 (edge group 0..7), c8 = (lane&7)*8 (col base, 16B)
__global__ __launch_bounds__(256) void k_aggr(const ushort* __restrict__ Y,
    const ushort* __restrict__ R, const float* __restrict__ brel,
    const int* __restrict__ deg, const int* __restrict__ csrp,
    ushort* __restrict__ hout, int do_relu){
  int node = blockIdx.x*4 + (threadIdx.x>>6);
  if (node >= NN) return;
  int lane = threadIdx.x & 63;
  int g = lane >> 3;
  int c8 = (lane & 7) << 3;
  int dc = deg[node]; if (dc > CAP) dc = CAP;
  const int* lst = csrp + (size_t)node*CAP;
  float a[8] = {0.f,0.f,0.f,0.f,0.f,0.f,0.f,0.f};
  int i = g;
  for (; i + 8 < dc; i += 16){          // pair: 16 edges in flight per wave
    int s0 = lst[i], s1 = lst[i+8];
    ushort8v y0 = *(const ushort8v*)&Y[(size_t)s0*64 + c8];
    ushort8v y1 = *(const ushort8v*)&Y[(size_t)s1*64 + c8];
    #pragma unroll
    for (int j=0;j<8;j++) a[j] += b2f(y0[j]) + b2f(y1[j]);
  }
  if (i < dc){
    int s0 = lst[i];
    ushort8v y0 = *(const ushort8v*)&Y[(size_t)s0*64 + c8];
    #pragma unroll
    for (int j=0;j<8;j++) a[j] += b2f(y0[j]);
  }
  #pragma unroll
  for (int j=0;j<8;j++){
    a[j] += __shfl_xor(a[j], 8);
    a[j] += __shfl_xor(a[j], 16);
    a[j] += __shfl_xor(a[j], 32);
  }
  if (g == 0){
    ushort8v r8 = *(const ushort8v*)&R[(size_t)node*64 + c8];
    float4 b0 = *(const float4*)&brel[c8];
    float4 b1 = *(const float4*)&brel[c8+4];
    float bb[8] = {b0.x,b0.y,b0.z,b0.w,b1.x,b1.y,b1.z,b1.w};
    ushort8v o;
    #pragma unroll
    for (int j=0;j<8;j++){
      float v = a[j] + b2f(r8[j]) + bb[j];
      if (do_relu) v = fmaxf(v, 0.f);
      o[j] = f2b(v);
    }
    *(ushort8v*)&hout[(size_t)node*64 + c8] = o;
  }
}

// ---------------- pooling ----------------
__global__ void k_ranges(const int* __restrict__ batch, int* __restrict__ gstart, int* __restrict__ gend){
  int g = blockIdx.x*blockDim.x + threadIdx.x;
  if (g >= NG) return;
  int lo=0, hi=NN;
  while (lo<hi){ int mid=(lo+hi)>>1; if (batch[mid] < g) lo=mid+1; else hi=mid; }
  int s = lo;
  lo=0; hi=NN;
  while (lo<hi){ int mid=(lo+hi)>>1; if (batch[mid] < g+1) lo=mid+1; else hi=mid; }
  gstart[g]=s; gend[g]=lo;
}

__global__ void k_pool(const ushort* __restrict__ h, const int* __restrict__ gstart,
                       const int* __restrict__ gend, float* __restrict__ pooled){
  int g = blockIdx.x;
  int lane = threadIdx.x & 63;
  int w = threadIdx.x >> 6;
  int beg = gstart[g], end = gend[g];
  float acc = 0.f;
  for (int n = beg + w; n < end; n += 4) acc += b2f(h[(size_t)n*64 + lane]);
  __shared__ float red[4][64];
  red[w][lane] = acc;
  __syncthreads();
  if (w == 0){
    float v = red[0][lane]+red[1][lane]+red[2][lane]+red[3][lane];
    int cnt = end - beg;
    pooled[g*64+lane] = v / fmaxf((float)cnt, 1.f);
  }
}

__global__ void k_final(const float* __restrict__ pooled, const float* __restrict__ Wlin,
                        const float* __restrict__ blin, float* __restrict__ out){
  __shared__ float sW[64*64];
  __shared__ float sP[4*64];
  int tid = threadIdx.x;
  for (int i=tid; i<4096; i+=256) sW[i] = Wlin[i];
  int g0 = blockIdx.x*4;
  { int g = g0 + tid/64; sP[tid] = (g<NG) ? pooled[g*64 + (tid&63)] : 0.f; }
  __syncthreads();
  int j = tid & 63, gl = tid >> 6;
  int g = g0 + gl;
  float acc = blin[j];
  for (int k=0;k<64;k++) acc += sP[gl*64+k]*sW[k*64+j];
  if (g < NG) out[g*64+j] = acc;
}

extern "C" void kernel_launch(void* const* d_in, const int* in_sizes, int n_in,
                              void* d_out, int out_size, void* d_ws, size_t ws_size,
                              hipStream_t stream){
  const float* x     = (const float*)d_in[0];
  const int*   ei    = (const int*)  d_in[1];
  const int*   batch = (const int*)  d_in[2];
  const float* Wrel1 = (const float*)d_in[3];
  const float* brel1 = (const float*)d_in[4];
  const float* Wroot1= (const float*)d_in[5];
  const float* Wrel2 = (const float*)d_in[6];
  const float* brel2 = (const float*)d_in[7];
  const float* Wroot2= (const float*)d_in[8];
  const float* Wrel3 = (const float*)d_in[9];
  const float* brel3 = (const float*)d_in[10];
  const float* Wroot3= (const float*)d_in[11];
  const float* Wlin  = (const float*)d_in[12];
  const float* blin  = (const float*)d_in[13];
  const int* src = ei;
  const int* dst = ei + NE;

  char* wsB = (char*)d_ws;
  size_t off = 0;
  auto alloc = [&](size_t bytes)->void*{
    void* p = wsB + off; off = (off + bytes + 255) & ~(size_t)255; return p;
  };
  int*      csrp   = (int*)     alloc((size_t)NN*CAP*4);   // 25.6 MB
  int*      deg    = (int*)     alloc((size_t)NN*4);
  int*      bcnt   = (int*)     alloc(NBK*4);
  int*      gbase  = (int*)     alloc(NBK*4);
  int*      gcur   = (int*)     alloc(NBK*4);
  unsigned* ebuf   = (unsigned*)alloc((size_t)NE*4);       // 6.4 MB packed
  ushort*   wp     = (ushort*)  alloc((size_t)3*8192*2);   // 48 KB
  ushort*   Y      = (ushort*)  alloc((size_t)NN*64*2);    // 12.8 MB
  ushort*   R      = (ushort*)  alloc((size_t)NN*64*2);    // 12.8 MB
  ushort*   h1     = (ushort*)  alloc((size_t)NN*64*2);    // 12.8 MB
  ushort*   h2     = (ushort*)  alloc((size_t)NN*64*2);    // 12.8 MB
  int*      gstart = (int*)     alloc(NG*4);
  int*      gend   = (int*)     alloc(NG*4);
  float*    pooled = (float*)   alloc(NG*64*4);

  hipMemsetAsync(deg, 0, (size_t)NN*4, stream);
  hipMemsetAsync(bcnt, 0, NBK*4, stream);

  k_wpack3  <<<(3*8192+255)/256,256,0,stream>>>(Wrel1,Wroot1,Wrel2,Wroot2,Wrel3,Wroot3, wp);
  k_bhist   <<<256,256,0,stream>>>(dst, bcnt);
  k_bscan   <<<1,512,0,stream>>>(bcnt, gbase, gcur);
  k_bscatter<<<256,256,0,stream>>>(src, dst, gcur, ebuf);
  k_bfill   <<<NBK,256,0,stream>>>(ebuf, gbase, bcnt, deg, csrp);

  int gb = (NN+63)/64;
  int ab = (NN+3)/4;

  // layer 1 (A = x, f32, cast fused into GEMM)
  k_gemm_mfma<<<gb,256,0,stream>>>(x,  1, wp + 0*8192, Y, R);
  k_aggr     <<<ab,256,0,stream>>>(Y, R, brel1, deg, csrp, h1, 1);
  // layer 2
  k_gemm_mfma<<<gb,256,0,stream>>>(h1, 0, wp + 1*8192, Y, R);
  k_aggr     <<<ab,256,0,stream>>>(Y, R, brel2, deg, csrp, h2, 1);
  // layer 3 (no relu)
  k_gemm_mfma<<<gb,256,0,stream>>>(h2, 0, wp + 2*8192, Y, R);
  k_aggr     <<<ab,256,0,stream>>>(Y, R, brel3, deg, csrp, h1, 0);

  k_ranges<<<1,256,0,stream>>>(batch, gstart, gend);
  k_pool  <<<NG,256,0,stream>>>(h1, gstart, gend, pooled);
  k_final <<<NG/4,256,0,stream>>>(pooled, Wlin, blin, (float*)d_out);
}

// Round 10
// 291.111 us; speedup vs baseline: 6.7269x; 1.0292x over previous
//
#include <hip/hip_runtime.h>
#include <hip/hip_bf16.h>

#define NN 100000
#define NE 1600000
#define DD 64
#define NG 256
#define CAP 64     // padded CSR slots/node; Poisson(16): P(any deg>64) ~ 2e-13
#define SHIFT 8    // 256 nodes per bucket
#define NBK 391    // ceil(NN/256)
#define CHUNK 6250 // edges per scatter block (256 blocks)

typedef __attribute__((ext_vector_type(8))) short bf16x8;
typedef __attribute__((ext_vector_type(4))) float f32x4;
typedef __attribute__((ext_vector_type(8))) unsigned short ushort8v;

__device__ __forceinline__ float b2f(ushort u){
  unsigned v = ((unsigned)u) << 16;
  return __uint_as_float(v);
}
__device__ __forceinline__ ushort f2b(float f){
  __hip_bfloat16 b = __float2bfloat16(f);
  return *(ushort*)&b;
}

// ---------------- bucketed edge grouping (dst-local, packed 4B) ----------------
__global__ void k_bhist(const int* __restrict__ dst, int* __restrict__ bcnt){
  __shared__ int h[NBK];
  for (int i=threadIdx.x; i<NBK; i+=256) h[i]=0;
  __syncthreads();
  const int stride = 256*256;
  for (int e = blockIdx.x*256 + threadIdx.x; e < NE; e += stride)
    atomicAdd(&h[dst[e]>>SHIFT], 1);
  __syncthreads();
  for (int i=threadIdx.x; i<NBK; i+=256) if (h[i]) atomicAdd(&bcnt[i], h[i]);
}

__global__ void k_bscan(const int* __restrict__ bcnt, int* __restrict__ gbase, int* __restrict__ gcur){
  __shared__ int s[512];
  int t = threadIdx.x;
  int v = (t < NBK) ? bcnt[t] : 0;
  s[t] = v;
  __syncthreads();
  for (int off=1; off<512; off<<=1){
    int u = (t >= off) ? s[t-off] : 0;
    __syncthreads();
    s[t] += u;
    __syncthreads();
  }
  if (t < NBK){ int b = s[t] - v; gbase[t] = b; gcur[t] = b; }
}

__global__ __launch_bounds__(256) void k_bscatter(const int* __restrict__ src, const int* __restrict__ dst,
                           int* __restrict__ gcur, unsigned* __restrict__ ebuf){
  __shared__ int h[NBK];
  __shared__ int base[NBK];
  __shared__ int lcur[NBK];
  for (int i=threadIdx.x; i<NBK; i+=256) h[i]=0;
  __syncthreads();
  const int e0 = blockIdx.x*CHUNK;
  const int e1 = min(e0+CHUNK, NE);
  for (int e=e0+threadIdx.x; e<e1; e+=256) atomicAdd(&h[dst[e]>>SHIFT], 1);
  __syncthreads();
  for (int i=threadIdx.x; i<NBK; i+=256){
    base[i] = h[i] ? atomicAdd(&gcur[i], h[i]) : 0;
    lcur[i] = 0;
  }
  __syncthreads();
  for (int e=e0+threadIdx.x; e<e1; e+=256){
    int d = dst[e];
    int b = d >> SHIFT;
    int r = atomicAdd(&lcur[b], 1);
    ebuf[base[b]+r] = ((unsigned)(d & 255) << 17) | (unsigned)src[e];   // 8b local-dst | 17b src
  }
}

// per-bucket blocks: node id reconstructed from blockIdx; 64KB csrp window -> L2-local writes
__global__ void k_bfill(const unsigned* __restrict__ ebuf, const int* __restrict__ gbase,
                        const int* __restrict__ bcnt, int* __restrict__ deg, int* __restrict__ csrp){
  int b = blockIdx.x;
  int beg = gbase[b], cnt = bcnt[b];
  for (int i = threadIdx.x; i < cnt; i += 256){
    unsigned p = ebuf[beg+i];
    int d = (b << SHIFT) | (int)(p >> 17);
    int q = atomicAdd(&deg[d], 1);
    if (q < CAP) csrp[(size_t)d*CAP + q] = (int)(p & 0x1FFFFu);
  }
}

// ---------------- weight packing ----------------
// wp layout per layer: [s(2)][t(8)][lane(64)][j(8)] bf16
// value = W[k][col], k = s*32 + (lane>>4)*8 + j, col = t*16 + (lane&15)
__global__ void k_wpack3(const float* __restrict__ Wr1, const float* __restrict__ Wo1,
                         const float* __restrict__ Wr2, const float* __restrict__ Wo2,
                         const float* __restrict__ Wr3, const float* __restrict__ Wo3,
                         ushort* __restrict__ wp){
  int i = blockIdx.x*256 + threadIdx.x;
  if (i >= 3*8192) return;
  int lay = i >> 13;
  int r = i & 8191;
  int j = r & 7, l = (r>>3) & 63, t = (r>>9) & 7, s = r >> 12;
  int k = s*32 + ((l>>4)<<3) + j;
  int col = t*16 + (l&15);
  const float* Wrel  = (lay==0) ? Wr1 : (lay==1) ? Wr2 : Wr3;
  const float* Wroot = (lay==0) ? Wo1 : (lay==1) ? Wo2 : Wo3;
  float v = (col < 64) ? Wrel[k*64 + col] : Wroot[k*64 + (col-64)];
  wp[i] = f2b(v);
}

// ---------------- MFMA dual GEMM: [Y | R] = A @ [Wrel | Wroot] ----------------
// A: f32 [NN][64] (aIsF32=1, layer 1) or bf16 [NN][64]. No LDS, no barriers.
__global__ __launch_bounds__(256) void k_gemm_mfma(const void* __restrict__ Av, int aIsF32,
    const ushort* __restrict__ wp, ushort* __restrict__ Y, ushort* __restrict__ Rr){
  const int w = threadIdx.x >> 6, l = threadIdx.x & 63;
  const int m = l & 15, kg = l >> 4;
  const int row0 = blockIdx.x*64 + w*16;
  int arow = row0 + m; if (arow >= NN) arow = NN-1;   // clamp; stores are guarded
  bf16x8 a0, a1;
  if (aIsF32){
    const float* Af = (const float*)Av;
    float4 f0 = *(const float4*)&Af[(size_t)arow*64 + kg*8];
    float4 f1 = *(const float4*)&Af[(size_t)arow*64 + kg*8 + 4];
    float4 f2 = *(const float4*)&Af[(size_t)arow*64 + 32 + kg*8];
    float4 f3 = *(const float4*)&Af[(size_t)arow*64 + 32 + kg*8 + 4];
    a0[0]=(short)f2b(f0.x); a0[1]=(short)f2b(f0.y); a0[2]=(short)f2b(f0.z); a0[3]=(short)f2b(f0.w);
    a0[4]=(short)f2b(f1.x); a0[5]=(short)f2b(f1.y); a0[6]=(short)f2b(f1.z); a0[7]=(short)f2b(f1.w);
    a1[0]=(short)f2b(f2.x); a1[1]=(short)f2b(f2.y); a1[2]=(short)f2b(f2.z); a1[3]=(short)f2b(f2.w);
    a1[4]=(short)f2b(f3.x); a1[5]=(short)f2b(f3.y); a1[6]=(short)f2b(f3.z); a1[7]=(short)f2b(f3.w);
  } else {
    const ushort* Ab = (const ushort*)Av;
    a0 = *(const bf16x8*)&Ab[(size_t)arow*64 + kg*8];
    a1 = *(const bf16x8*)&Ab[(size_t)arow*64 + 32 + kg*8];
  }
  f32x4 acc[8];
  #pragma unroll
  for (int t=0; t<8; t++){
    bf16x8 b0 = *(const bf16x8*)&wp[((size_t)(0*8+t)*64 + l)*8];
    bf16x8 b1 = *(const bf16x8*)&wp[((size_t)(1*8+t)*64 + l)*8];
    f32x4 c = {0.f, 0.f, 0.f, 0.f};
    c = __builtin_amdgcn_mfma_f32_16x16x32_bf16(a0, b0, c, 0, 0, 0);
    c = __builtin_amdgcn_mfma_f32_16x16x32_bf16(a1, b1, c, 0, 0, 0);
    acc[t] = c;
  }
  #pragma unroll
  for (int t=0; t<8; t++){
    #pragma unroll
    for (int reg=0; reg<4; reg++){
      int row = row0 + kg*4 + reg;       // D: row = (lane>>4)*4 + reg, col = lane&15
      if (row < NN){
        ushort o = f2b(acc[t][reg]);
        if (t < 4) Y [(size_t)row*64 + t*16 + m]     = o;
        else       Rr[(size_t)row*64 + (t-4)*16 + m] = o;
      }
    }
  }
}

// ---------------- gather-aggregate v3: 4 nodes/wave, 16 masked loads in flight ----------------
// lane: g = lane>>3 (edge group 0..7), c8 = (lane&7)*8 (col base, 16B)
// indices for slots 0..31 of nodes m,m+1 preloaded in one 256B wave-load, shfl-distributed.
__global__ __launch_bounds__(256) void k_aggr(const ushort* __restrict__ Y,
    const ushort* __restrict__ R, const float* __restrict__ brel,
    const int* __restrict__ deg, const int* __restrict__ csrp,
    ushort* __restrict__ hout, int do_relu){
  const int w = threadIdx.x >> 6, lane = threadIdx.x & 63;
  const int g = lane >> 3, c8 = (lane & 7) << 3;
  const int nbase = blockIdx.x*16 + w*4;      // 4 nodes per wave
  const int half = lane >> 5, l32 = lane & 31;

  // degrees
  int dcv[4];
  #pragma unroll
  for (int m=0;m<4;m++){
    int nn = nbase+m; if (nn >= NN) nn = NN-1;
    dcv[m] = min(deg[nn], CAP);
  }
  // slot 0..31 indices: idxA -> nodes 0(lanes 0-31),1(lanes 32-63); idxB -> nodes 2,3
  int nnA = nbase + half;     if (nnA >= NN) nnA = NN-1;
  int nnB = nbase + 2 + half; if (nnB >= NN) nnB = NN-1;
  int idxA = csrp[(size_t)nnA*CAP + l32];
  int idxB = csrp[(size_t)nnB*CAP + l32];

  // issue 4 masked row-loads per node (slots g, g+8, g+16, g+24)
  ushort8v y[4][4];
  float    mk[4][4];
  #pragma unroll
  for (int m=0;m<4;m++){
    int reg = (m < 2);
    #pragma unroll
    for (int p=0;p<4;p++){
      int slot = g + 8*p;
      int s = __shfl(reg ? idxA : idxB, ((m&1)<<5) + slot);
      bool valid = slot < dcv[m];
      mk[m][p] = valid ? 1.f : 0.f;
      s = valid ? s : 0;
      y[m][p] = *(const ushort8v*)&Y[((size_t)s<<6) + c8];
    }
  }

  #pragma unroll
  for (int m=0;m<4;m++){
    int node = nbase + m;
    float a[8];
    #pragma unroll
    for (int j=0;j<8;j++)
      a[j] = b2f(y[m][0][j])*mk[m][0] + b2f(y[m][1][j])*mk[m][1]
           + b2f(y[m][2][j])*mk[m][2] + b2f(y[m][3][j])*mk[m][3];
    // rare tail: deg > 32 (on-demand, divergent-safe)
    if (dcv[m] > 32){
      int nn = node; if (nn >= NN) nn = NN-1;
      const int* lst = csrp + (size_t)nn*CAP;
      for (int i = 32 + g; i < dcv[m]; i += 8){
        int s = lst[i];
        ushort8v yy = *(const ushort8v*)&Y[((size_t)s<<6) + c8];
        #pragma unroll
        for (int j=0;j<8;j++) a[j] += b2f(yy[j]);
      }
    }
    #pragma unroll
    for (int j=0;j<8;j++){
      a[j] += __shfl_xor(a[j], 8);
      a[j] += __shfl_xor(a[j], 16);
      a[j] += __shfl_xor(a[j], 32);
    }
    if (g == 0 && node < NN){
      ushort8v r8 = *(const ushort8v*)&R[((size_t)node<<6) + c8];
      float4 b0 = *(const float4*)&brel[c8];
      float4 b1 = *(const float4*)&brel[c8+4];
      float bb[8] = {b0.x,b0.y,b0.z,b0.w,b1.x,b1.y,b1.z,b1.w};
      ushort8v o;
      #pragma unroll
      for (int j=0;j<8;j++){
        float v = a[j] + b2f(r8[j]) + bb[j];
        if (do_relu) v = fmaxf(v, 0.f);
        o[j] = f2b(v);
      }
      *(ushort8v*)&hout[((size_t)node<<6) + c8] = o;
    }
  }
}

// ---------------- pooling (ranges fused: per-block binary search, uniform) ----------------
__global__ void k_pool(const ushort* __restrict__ h, const int* __restrict__ batch,
                       float* __restrict__ pooled){
  int g = blockIdx.x;
  int lo=0, hi=NN;
  while (lo<hi){ int mid=(lo+hi)>>1; if (batch[mid] < g) lo=mid+1; else hi=mid; }
  int beg = lo;
  lo=0; hi=NN;
  while (lo<hi){ int mid=(lo+hi)>>1; if (batch[mid] < g+1) lo=mid+1; else hi=mid; }
  int end = lo;
  int lane = threadIdx.x & 63;
  int w = threadIdx.x >> 6;
  float acc = 0.f;
  for (int n = beg + w; n < end; n += 4) acc += b2f(h[(size_t)n*64 + lane]);
  __shared__ float red[4][64];
  red[w][lane] = acc;
  __syncthreads();
  if (w == 0){
    float v = red[0][lane]+red[1][lane]+red[2][lane]+red[3][lane];
    int cnt = end - beg;
    pooled[g*64+lane] = v / fmaxf((float)cnt, 1.f);
  }
}

__global__ void k_final(const float* __restrict__ pooled, const float* __restrict__ Wlin,
                        const float* __restrict__ blin, float* __restrict__ out){
  __shared__ float sW[64*64];
  __shared__ float sP[4*64];
  int tid = threadIdx.x;
  for (int i=tid; i<4096; i+=256) sW[i] = Wlin[i];
  int g0 = blockIdx.x*4;
  { int g = g0 + tid/64; sP[tid] = (g<NG) ? pooled[g*64 + (tid&63)] : 0.f; }
  __syncthreads();
  int j = tid & 63, gl = tid >> 6;
  int g = g0 + gl;
  float acc = blin[j];
  for (int k=0;k<64;k++) acc += sP[gl*64+k]*sW[k*64+j];
  if (g < NG) out[g*64+j] = acc;
}

extern "C" void kernel_launch(void* const* d_in, const int* in_sizes, int n_in,
                              void* d_out, int out_size, void* d_ws, size_t ws_size,
                              hipStream_t stream){
  const float* x     = (const float*)d_in[0];
  const int*   ei    = (const int*)  d_in[1];
  const int*   batch = (const int*)  d_in[2];
  const float* Wrel1 = (const float*)d_in[3];
  const float* brel1 = (const float*)d_in[4];
  const float* Wroot1= (const float*)d_in[5];
  const float* Wrel2 = (const float*)d_in[6];
  const float* brel2 = (const float*)d_in[7];
  const float* Wroot2= (const float*)d_in[8];
  const float* Wrel3 = (const float*)d_in[9];
  const float* brel3 = (const float*)d_in[10];
  const float* Wroot3= (const float*)d_in[11];
  const float* Wlin  = (const float*)d_in[12];
  const float* blin  = (const float*)d_in[13];
  const int* src = ei;
  const int* dst = ei + NE;

  char* wsB = (char*)d_ws;
  size_t off = 0;
  auto alloc = [&](size_t bytes)->void*{
    void* p = wsB + off; off = (off + bytes + 255) & ~(size_t)255; return p;
  };
  int*      csrp   = (int*)     alloc((size_t)NN*CAP*4);   // 25.6 MB
  int*      deg    = (int*)     alloc((size_t)NN*4);
  int*      bcnt   = (int*)     alloc(NBK*4);
  int*      gbase  = (int*)     alloc(NBK*4);
  int*      gcur   = (int*)     alloc(NBK*4);
  unsigned* ebuf   = (unsigned*)alloc((size_t)NE*4);       // 6.4 MB packed
  ushort*   wp     = (ushort*)  alloc((size_t)3*8192*2);   // 48 KB
  ushort*   Y      = (ushort*)  alloc((size_t)NN*64*2);    // 12.8 MB
  ushort*   R      = (ushort*)  alloc((size_t)NN*64*2);    // 12.8 MB
  ushort*   h1     = (ushort*)  alloc((size_t)NN*64*2);    // 12.8 MB
  ushort*   h2     = (ushort*)  alloc((size_t)NN*64*2);    // 12.8 MB
  float*    pooled = (float*)   alloc(NG*64*4);

  hipMemsetAsync(deg, 0, (size_t)NN*4, stream);
  hipMemsetAsync(bcnt, 0, NBK*4, stream);

  k_wpack3  <<<(3*8192+255)/256,256,0,stream>>>(Wrel1,Wroot1,Wrel2,Wroot2,Wrel3,Wroot3, wp);
  k_bhist   <<<256,256,0,stream>>>(dst, bcnt);
  k_bscan   <<<1,512,0,stream>>>(bcnt, gbase, gcur);
  k_bscatter<<<256,256,0,stream>>>(src, dst, gcur, ebuf);
  k_bfill   <<<NBK,256,0,stream>>>(ebuf, gbase, bcnt, deg, csrp);

  int gb = (NN+63)/64;
  int ab = (NN+15)/16;   // 16 nodes per block (4 waves x 4 nodes)

  // layer 1 (A = x, f32, cast fused into GEMM)
  k_gemm_mfma<<<gb,256,0,stream>>>(x,  1, wp + 0*8192, Y, R);
  k_aggr     <<<ab,256,0,stream>>>(Y, R, brel1, deg, csrp, h1, 1);
  // layer 2
  k_gemm_mfma<<<gb,256,0,stream>>>(h1, 0, wp + 1*8192, Y, R);
  k_aggr     <<<ab,256,0,stream>>>(Y, R, brel2, deg, csrp, h2, 1);
  // layer 3 (no relu)
  k_gemm_mfma<<<gb,256,0,stream>>>(h2, 0, wp + 2*8192, Y, R);
  k_aggr     <<<ab,256,0,stream>>>(Y, R, brel3, deg, csrp, h1, 0);

  k_pool <<<NG,256,0,stream>>>(h1, batch, pooled);
  k_final<<<NG/4,256,0,stream>>>(pooled, Wlin, blin, (float*)d_out);
}

// Round 11
// 261.661 us; speedup vs baseline: 7.4840x; 1.1125x over previous
//
#include <hip/hip_runtime.h>
#include <hip/hip_bf16.h>

#define NN 100000
#define NE 1600000
#define DD 64
#define NG 256
#define SHIFT 8    // 256 nodes per bucket
#define NBK 391    // ceil(NN/256)
#define NSB 256    // scatter blocks
#define CHUNK 6250 // edges per scatter block

typedef __attribute__((ext_vector_type(8))) short bf16x8;
typedef __attribute__((ext_vector_type(4))) float f32x4;
typedef __attribute__((ext_vector_type(8))) unsigned short ushort8v;

__device__ __forceinline__ float b2f(ushort u){
  unsigned v = ((unsigned)u) << 16;
  return __uint_as_float(v);
}
__device__ __forceinline__ ushort f2b(float f){
  __hip_bfloat16 b = __float2bfloat16(f);
  return *(ushort*)&b;
}

// ---------------- stage 1: per-(block,bucket) counts ----------------
__global__ __launch_bounds__(256) void k_cnt(const int* __restrict__ dst, int* __restrict__ cntmat){
  __shared__ int h[NBK];
  for (int i=threadIdx.x; i<NBK; i+=256) h[i]=0;
  __syncthreads();
  const int e0 = blockIdx.x*CHUNK;
  const int e1 = min(e0+CHUNK, NE);
  for (int e=e0+threadIdx.x; e<e1; e+=256) atomicAdd(&h[dst[e]>>SHIFT], 1);
  __syncthreads();
  for (int i=threadIdx.x; i<NBK; i+=256) cntmat[i*NSB + blockIdx.x] = h[i];
}

// ---------------- stage 2: per-bucket scan over blocks (in place) ----------------
__global__ __launch_bounds__(256) void k_colscan(int* __restrict__ cntmat, int* __restrict__ bcnt){
  __shared__ int s[256];
  const int b = blockIdx.x, t = threadIdx.x;
  int v = cntmat[b*NSB + t];
  s[t] = v;
  __syncthreads();
  for (int off=1; off<256; off<<=1){
    int u = (t >= off) ? s[t-off] : 0;
    __syncthreads();
    s[t] += u;
    __syncthreads();
  }
  cntmat[b*NSB + t] = s[t] - v;           // exclusive within bucket
  if (t == 255) bcnt[b] = s[255];
}

// ---------------- stage 3: scan bucket totals ----------------
__global__ void k_bscan(const int* __restrict__ bcnt, int* __restrict__ gbase){
  __shared__ int s[512];
  int t = threadIdx.x;
  int v = (t < NBK) ? bcnt[t] : 0;
  s[t] = v;
  __syncthreads();
  for (int off=1; off<512; off<<=1){
    int u = (t >= off) ? s[t-off] : 0;
    __syncthreads();
    s[t] += u;
    __syncthreads();
  }
  if (t < NBK) gbase[t] = s[t] - v;
  if (t == 0) gbase[NBK] = NE;
}

// ---------------- stage 4: scatter edges into bucket-grouped ebuf ----------------
__global__ __launch_bounds__(256) void k_bscatter(const int* __restrict__ src, const int* __restrict__ dst,
                           const int* __restrict__ gbase, const int* __restrict__ cntmat,
                           unsigned* __restrict__ ebuf){
  __shared__ int base[NBK];
  __shared__ int lcur[NBK];
  const int blk = blockIdx.x;
  for (int i=threadIdx.x; i<NBK; i+=256){
    base[i] = gbase[i] + cntmat[i*NSB + blk];
    lcur[i] = 0;
  }
  __syncthreads();
  const int e0 = blk*CHUNK;
  const int e1 = min(e0+CHUNK, NE);
  for (int e=e0+threadIdx.x; e<e1; e+=256){
    int d = dst[e];
    int b = d >> SHIFT;
    int r = atomicAdd(&lcur[b], 1);
    ebuf[base[b]+r] = ((unsigned)(d & 255) << 17) | (unsigned)src[e];   // 8b local-dst | 17b src
  }
}

// ---------------- stage 5: per-bucket LDS counting sort -> tight CSR + rowptr ----------------
__global__ __launch_bounds__(256) void k_bfill(const unsigned* __restrict__ ebuf, const int* __restrict__ gbase,
                        int* __restrict__ rowptr, int* __restrict__ csr){
  __shared__ int c[256];
  __shared__ int lbase[256];
  __shared__ int lcur[256];
  const int b = blockIdx.x, t = threadIdx.x;
  const int beg = gbase[b], cnt = gbase[b+1] - beg;
  c[t] = 0;
  __syncthreads();
  for (int i=t; i<cnt; i+=256) atomicAdd(&c[ebuf[beg+i]>>17], 1);
  __syncthreads();
  int v = c[t];
  __shared__ int s[256];
  s[t] = v;
  __syncthreads();
  for (int off=1; off<256; off<<=1){
    int u = (t >= off) ? s[t-off] : 0;
    __syncthreads();
    s[t] += u;
    __syncthreads();
  }
  int excl = s[t] - v;
  lbase[t] = excl; lcur[t] = excl;
  int node = (b << SHIFT) + t;
  if (node < NN) rowptr[node] = beg + excl;
  if (b == NBK-1 && t == 0) rowptr[NN] = NE;
  __syncthreads();
  for (int i=t; i<cnt; i+=256){
    unsigned p = ebuf[beg+i];
    int dl = (int)(p >> 17);
    int r = atomicAdd(&lcur[dl], 1);
    csr[beg + r] = (int)(p & 0x1FFFFu);
  }
}

// ---------------- weight packing ----------------
// wp layout per layer: [s(2)][t(8)][lane(64)][j(8)] bf16
// value = W[k][col], k = s*32 + (lane>>4)*8 + j, col = t*16 + (lane&15)
__global__ void k_wpack3(const float* __restrict__ Wr1, const float* __restrict__ Wo1,
                         const float* __restrict__ Wr2, const float* __restrict__ Wo2,
                         const float* __restrict__ Wr3, const float* __restrict__ Wo3,
                         ushort* __restrict__ wp){
  int i = blockIdx.x*256 + threadIdx.x;
  if (i >= 3*8192) return;
  int lay = i >> 13;
  int r = i & 8191;
  int j = r & 7, l = (r>>3) & 63, t = (r>>9) & 7, s = r >> 12;
  int k = s*32 + ((l>>4)<<3) + j;
  int col = t*16 + (l&15);
  const float* Wrel  = (lay==0) ? Wr1 : (lay==1) ? Wr2 : Wr3;
  const float* Wroot = (lay==0) ? Wo1 : (lay==1) ? Wo2 : Wo3;
  float v = (col < 64) ? Wrel[k*64 + col] : Wroot[k*64 + (col-64)];
  wp[i] = f2b(v);
}

// ---------------- MFMA dual GEMM: [Y | R] = A @ [Wrel | Wroot] ----------------
__global__ __launch_bounds__(256) void k_gemm_mfma(const void* __restrict__ Av, int aIsF32,
    const ushort* __restrict__ wp, ushort* __restrict__ Y, ushort* __restrict__ Rr){
  const int w = threadIdx.x >> 6, l = threadIdx.x & 63;
  const int m = l & 15, kg = l >> 4;
  const int row0 = blockIdx.x*64 + w*16;
  int arow = row0 + m; if (arow >= NN) arow = NN-1;   // clamp; stores are guarded
  bf16x8 a0, a1;
  if (aIsF32){
    const float* Af = (const float*)Av;
    float4 f0 = *(const float4*)&Af[(size_t)arow*64 + kg*8];
    float4 f1 = *(const float4*)&Af[(size_t)arow*64 + kg*8 + 4];
    float4 f2 = *(const float4*)&Af[(size_t)arow*64 + 32 + kg*8];
    float4 f3 = *(const float4*)&Af[(size_t)arow*64 + 32 + kg*8 + 4];
    a0[0]=(short)f2b(f0.x); a0[1]=(short)f2b(f0.y); a0[2]=(short)f2b(f0.z); a0[3]=(short)f2b(f0.w);
    a0[4]=(short)f2b(f1.x); a0[5]=(short)f2b(f1.y); a0[6]=(short)f2b(f1.z); a0[7]=(short)f2b(f1.w);
    a1[0]=(short)f2b(f2.x); a1[1]=(short)f2b(f2.y); a1[2]=(short)f2b(f2.z); a1[3]=(short)f2b(f2.w);
    a1[4]=(short)f2b(f3.x); a1[5]=(short)f2b(f3.y); a1[6]=(short)f2b(f3.z); a1[7]=(short)f2b(f3.w);
  } else {
    const ushort* Ab = (const ushort*)Av;
    a0 = *(const bf16x8*)&Ab[(size_t)arow*64 + kg*8];
    a1 = *(const bf16x8*)&Ab[(size_t)arow*64 + 32 + kg*8];
  }
  f32x4 acc[8];
  #pragma unroll
  for (int t=0; t<8; t++){
    bf16x8 b0 = *(const bf16x8*)&wp[((size_t)(0*8+t)*64 + l)*8];
    bf16x8 b1 = *(const bf16x8*)&wp[((size_t)(1*8+t)*64 + l)*8];
    f32x4 c = {0.f, 0.f, 0.f, 0.f};
    c = __builtin_amdgcn_mfma_f32_16x16x32_bf16(a0, b0, c, 0, 0, 0);
    c = __builtin_amdgcn_mfma_f32_16x16x32_bf16(a1, b1, c, 0, 0, 0);
    acc[t] = c;
  }
  #pragma unroll
  for (int t=0; t<8; t++){
    #pragma unroll
    for (int reg=0; reg<4; reg++){
      int row = row0 + kg*4 + reg;       // D: row = (lane>>4)*4 + reg, col = lane&15
      if (row < NN){
        ushort o = f2b(acc[t][reg]);
        if (t < 4) Y [(size_t)row*64 + t*16 + m]     = o;
        else       Rr[(size_t)row*64 + (t-4)*16 + m] = o;
      }
    }
  }
}

// ---------------- gather-aggregate: 8 lanes/edge (ushort8), tight CSR ----------------
__global__ __launch_bounds__(256) void k_aggr(const ushort* __restrict__ Y,
    const ushort* __restrict__ R, const float* __restrict__ brel,
    const int* __restrict__ rowptr, const int* __restrict__ csr,
    ushort* __restrict__ hout, int do_relu){
  int node = blockIdx.x*4 + (threadIdx.x>>6);
  if (node >= NN) return;
  int lane = threadIdx.x & 63;
  int g = lane >> 3;
  int c8 = (lane & 7) << 3;
  int beg = rowptr[node];
  int dc = rowptr[node+1] - beg;
  const int* lst = csr + beg;
  float a[8] = {0.f,0.f,0.f,0.f,0.f,0.f,0.f,0.f};
  int i = g;
  for (; i + 8 < dc; i += 16){          // pair: 16 edges in flight per wave
    int s0 = lst[i], s1 = lst[i+8];
    ushort8v y0 = *(const ushort8v*)&Y[((size_t)s0<<6) + c8];
    ushort8v y1 = *(const ushort8v*)&Y[((size_t)s1<<6) + c8];
    #pragma unroll
    for (int j=0;j<8;j++) a[j] += b2f(y0[j]) + b2f(y1[j]);
  }
  if (i < dc){
    int s0 = lst[i];
    ushort8v y0 = *(const ushort8v*)&Y[((size_t)s0<<6) + c8];
    #pragma unroll
    for (int j=0;j<8;j++) a[j] += b2f(y0[j]);
  }
  #pragma unroll
  for (int j=0;j<8;j++){
    a[j] += __shfl_xor(a[j], 8);
    a[j] += __shfl_xor(a[j], 16);
    a[j] += __shfl_xor(a[j], 32);
  }
  if (g == 0){
    ushort8v r8 = *(const ushort8v*)&R[((size_t)node<<6) + c8];
    float4 b0 = *(const float4*)&brel[c8];
    float4 b1 = *(const float4*)&brel[c8+4];
    float bb[8] = {b0.x,b0.y,b0.z,b0.w,b1.x,b1.y,b1.z,b1.w};
    ushort8v o;
    #pragma unroll
    for (int j=0;j<8;j++){
      float v = a[j] + b2f(r8[j]) + bb[j];
      if (do_relu) v = fmaxf(v, 0.f);
      o[j] = f2b(v);
    }
    *(ushort8v*)&hout[((size_t)node<<6) + c8] = o;
  }
}

// ---------------- pooling + final linear fused ----------------
__global__ __launch_bounds__(256) void k_pool(const ushort* __restrict__ h, const int* __restrict__ batch,
                       const float* __restrict__ Wlin, const float* __restrict__ blin,
                       float* __restrict__ out){
  int g = blockIdx.x;
  int lo=0, hi=NN;
  while (lo<hi){ int mid=(lo+hi)>>1; if (batch[mid] < g) lo=mid+1; else hi=mid; }
  int beg = lo;
  lo=0; hi=NN;
  while (lo<hi){ int mid=(lo+hi)>>1; if (batch[mid] < g+1) lo=mid+1; else hi=mid; }
  int end = lo;
  int lane = threadIdx.x & 63;
  int w = threadIdx.x >> 6;
  float acc = 0.f;
  for (int n = beg + w; n < end; n += 4) acc += b2f(h[(size_t)n*64 + lane]);
  __shared__ float red[4][64];
  __shared__ float p[64];
  red[w][lane] = acc;
  __syncthreads();
  if (w == 0){
    float v = red[0][lane]+red[1][lane]+red[2][lane]+red[3][lane];
    int cnt = end - beg;
    p[lane] = v / fmaxf((float)cnt, 1.f);
  }
  __syncthreads();
  if (w == 0){
    float o = blin[lane];
    #pragma unroll 8
    for (int k=0;k<64;k++) o += p[k]*Wlin[k*64+lane];
    out[g*64+lane] = o;
  }
}

extern "C" void kernel_launch(void* const* d_in, const int* in_sizes, int n_in,
                              void* d_out, int out_size, void* d_ws, size_t ws_size,
                              hipStream_t stream){
  const float* x     = (const float*)d_in[0];
  const int*   ei    = (const int*)  d_in[1];
  const int*   batch = (const int*)  d_in[2];
  const float* Wrel1 = (const float*)d_in[3];
  const float* brel1 = (const float*)d_in[4];
  const float* Wroot1= (const float*)d_in[5];
  const float* Wrel2 = (const float*)d_in[6];
  const float* brel2 = (const float*)d_in[7];
  const float* Wroot2= (const float*)d_in[8];
  const float* Wrel3 = (const float*)d_in[9];
  const float* brel3 = (const float*)d_in[10];
  const float* Wroot3= (const float*)d_in[11];
  const float* Wlin  = (const float*)d_in[12];
  const float* blin  = (const float*)d_in[13];
  const int* src = ei;
  const int* dst = ei + NE;

  char* wsB = (char*)d_ws;
  size_t off = 0;
  auto alloc = [&](size_t bytes)->void*{
    void* p = wsB + off; off = (off + bytes + 255) & ~(size_t)255; return p;
  };
  int*      csr    = (int*)     alloc((size_t)NE*4);          // 6.4 MB tight
  int*      rowptr = (int*)     alloc((size_t)(NN+1)*4);
  int*      cntmat = (int*)     alloc((size_t)NBK*NSB*4);     // 400 KB
  int*      bcnt   = (int*)     alloc(NBK*4);
  int*      gbase  = (int*)     alloc((NBK+1)*4);
  unsigned* ebuf   = (unsigned*)alloc((size_t)NE*4);          // 6.4 MB packed
  ushort*   wp     = (ushort*)  alloc((size_t)3*8192*2);      // 48 KB
  ushort*   Y      = (ushort*)  alloc((size_t)NN*64*2);       // 12.8 MB
  ushort*   R      = (ushort*)  alloc((size_t)NN*64*2);       // 12.8 MB
  ushort*   h1     = (ushort*)  alloc((size_t)NN*64*2);       // 12.8 MB
  ushort*   h2     = (ushort*)  alloc((size_t)NN*64*2);       // 12.8 MB

  k_wpack3  <<<(3*8192+255)/256,256,0,stream>>>(Wrel1,Wroot1,Wrel2,Wroot2,Wrel3,Wroot3, wp);
  k_cnt     <<<NSB,256,0,stream>>>(dst, cntmat);
  k_colscan <<<NBK,256,0,stream>>>(cntmat, bcnt);
  k_bscan   <<<1,512,0,stream>>>(bcnt, gbase);
  k_bscatter<<<NSB,256,0,stream>>>(src, dst, gbase, cntmat, ebuf);
  k_bfill   <<<NBK,256,0,stream>>>(ebuf, gbase, rowptr, csr);

  int gb = (NN+63)/64;
  int ab = (NN+3)/4;

  // layer 1 (A = x, f32, cast fused into GEMM)
  k_gemm_mfma<<<gb,256,0,stream>>>(x,  1, wp + 0*8192, Y, R);
  k_aggr     <<<ab,256,0,stream>>>(Y, R, brel1, rowptr, csr, h1, 1);
  // layer 2
  k_gemm_mfma<<<gb,256,0,stream>>>(h1, 0, wp + 1*8192, Y, R);
  k_aggr     <<<ab,256,0,stream>>>(Y, R, brel2, rowptr, csr, h2, 1);
  // layer 3 (no relu)
  k_gemm_mfma<<<gb,256,0,stream>>>(h2, 0, wp + 2*8192, Y, R);
  k_aggr     <<<ab,256,0,stream>>>(Y, R, brel3, rowptr, csr, h1, 0);

  k_pool <<<NG,256,0,stream>>>(h1, batch, Wlin, blin, (float*)d_out);
}

// Round 12
// 256.840 us; speedup vs baseline: 7.6245x; 1.0188x over previous
//
#include <hip/hip_runtime.h>
#include <hip/hip_bf16.h>

#define NN 100000
#define NE 1600000
#define DD 64
#define NG 256
#define SHIFT 8     // 256 nodes per bucket
#define NBK 391     // ceil(NN/256)
#define BCAP 4608   // bucket capacity: mean 4092, +8 sigma
#define NSB 256     // scatter blocks
#define CHUNK 6250  // edges per scatter block

typedef __attribute__((ext_vector_type(8))) short bf16x8;
typedef __attribute__((ext_vector_type(4))) float f32x4;
typedef __attribute__((ext_vector_type(8))) unsigned short ushort8v;

__device__ __forceinline__ float b2f(ushort u){
  unsigned v = ((unsigned)u) << 16;
  return __uint_as_float(v);
}
__device__ __forceinline__ ushort f2b(float f){
  __hip_bfloat16 b = __float2bfloat16(f);
  return *(ushort*)&b;
}

// ---------------- weight packing + gcur init (fused) ----------------
// wp layout per layer: [s(2)][t(8)][lane(64)][j(8)] bf16
// value = W[k][col], k = s*32 + (lane>>4)*8 + j, col = t*16 + (lane&15)
__global__ void k_wpack3(const float* __restrict__ Wr1, const float* __restrict__ Wo1,
                         const float* __restrict__ Wr2, const float* __restrict__ Wo2,
                         const float* __restrict__ Wr3, const float* __restrict__ Wo3,
                         ushort* __restrict__ wp, int* __restrict__ gcur){
  int i = blockIdx.x*256 + threadIdx.x;
  if (i < NBK) gcur[i] = i*BCAP;          // fixed bucket bases
  if (i >= 3*8192) return;
  int lay = i >> 13;
  int r = i & 8191;
  int j = r & 7, l = (r>>3) & 63, t = (r>>9) & 7, s = r >> 12;
  int k = s*32 + ((l>>4)<<3) + j;
  int col = t*16 + (l&15);
  const float* Wrel  = (lay==0) ? Wr1 : (lay==1) ? Wr2 : Wr3;
  const float* Wroot = (lay==0) ? Wo1 : (lay==1) ? Wo2 : Wo3;
  float v = (col < 64) ? Wrel[k*64 + col] : Wroot[k*64 + (col-64)];
  wp[i] = f2b(v);
}

// ---------------- scatter: per-block hist -> reserve -> write packed edges ----------------
__global__ __launch_bounds__(256) void k_bscatter(const int* __restrict__ src, const int* __restrict__ dst,
                           int* __restrict__ gcur, unsigned* __restrict__ ebuf){
  __shared__ int h[NBK];
  __shared__ int base[NBK];
  __shared__ int lcur[NBK];
  for (int i=threadIdx.x; i<NBK; i+=256) h[i]=0;
  __syncthreads();
  const int e0 = blockIdx.x*CHUNK;
  const int e1 = min(e0+CHUNK, NE);
  for (int e=e0+threadIdx.x; e<e1; e+=256) atomicAdd(&h[dst[e]>>SHIFT], 1);
  __syncthreads();
  for (int i=threadIdx.x; i<NBK; i+=256){
    base[i] = h[i] ? atomicAdd(&gcur[i], h[i]) : 0;
    lcur[i] = 0;
  }
  __syncthreads();
  for (int e=e0+threadIdx.x; e<e1; e+=256){
    int d = dst[e];
    int b = d >> SHIFT;
    int r = atomicAdd(&lcur[b], 1);
    size_t idx = (size_t)base[b] + r;
    if (idx < (size_t)NBK*BCAP)
      ebuf[idx] = ((unsigned)(d & 255) << 17) | (unsigned)src[e];   // 8b local-dst | 17b src
  }
}

// ---------------- per-bucket LDS counting sort -> bucket-padded CSR + rowptr + deg ----------------
__global__ __launch_bounds__(256) void k_bfill(const unsigned* __restrict__ ebuf, const int* __restrict__ gcur,
                        int* __restrict__ rowptr, int* __restrict__ degarr, int* __restrict__ csr){
  __shared__ int c[256];
  __shared__ int lcur[256];
  __shared__ int s[256];
  __shared__ int scnt;
  const int b = blockIdx.x, t = threadIdx.x;
  const int ebase = b*BCAP;
  if (t == 0) scnt = min(gcur[b] - ebase, BCAP);
  c[t] = 0;
  __syncthreads();
  const int cnt = scnt;
  for (int i=t; i<cnt; i+=256) atomicAdd(&c[ebuf[ebase+i]>>17], 1);
  __syncthreads();
  int v = c[t];
  s[t] = v;
  __syncthreads();
  for (int off=1; off<256; off<<=1){
    int u = (t >= off) ? s[t-off] : 0;
    __syncthreads();
    s[t] += u;
    __syncthreads();
  }
  int excl = s[t] - v;
  lcur[t] = excl;
  int node = (b << SHIFT) + t;
  if (node < NN){ rowptr[node] = ebase + excl; degarr[node] = v; }
  __syncthreads();
  for (int i=t; i<cnt; i+=256){
    unsigned p = ebuf[ebase+i];
    int dl = (int)(p >> 17);
    int r = atomicAdd(&lcur[dl], 1);
    csr[ebase + r] = (int)(p & 0x1FFFFu);
  }
}

// ---------------- MFMA dual GEMM: [Y | R] = A @ [Wrel | Wroot] ----------------
__global__ __launch_bounds__(256) void k_gemm_mfma(const void* __restrict__ Av, int aIsF32,
    const ushort* __restrict__ wp, ushort* __restrict__ Y, ushort* __restrict__ Rr){
  const int w = threadIdx.x >> 6, l = threadIdx.x & 63;
  const int m = l & 15, kg = l >> 4;
  const int row0 = blockIdx.x*64 + w*16;
  int arow = row0 + m; if (arow >= NN) arow = NN-1;   // clamp; stores are guarded
  bf16x8 a0, a1;
  if (aIsF32){
    const float* Af = (const float*)Av;
    float4 f0 = *(const float4*)&Af[(size_t)arow*64 + kg*8];
    float4 f1 = *(const float4*)&Af[(size_t)arow*64 + kg*8 + 4];
    float4 f2 = *(const float4*)&Af[(size_t)arow*64 + 32 + kg*8];
    float4 f3 = *(const float4*)&Af[(size_t)arow*64 + 32 + kg*8 + 4];
    a0[0]=(short)f2b(f0.x); a0[1]=(short)f2b(f0.y); a0[2]=(short)f2b(f0.z); a0[3]=(short)f2b(f0.w);
    a0[4]=(short)f2b(f1.x); a0[5]=(short)f2b(f1.y); a0[6]=(short)f2b(f1.z); a0[7]=(short)f2b(f1.w);
    a1[0]=(short)f2b(f2.x); a1[1]=(short)f2b(f2.y); a1[2]=(short)f2b(f2.z); a1[3]=(short)f2b(f2.w);
    a1[4]=(short)f2b(f3.x); a1[5]=(short)f2b(f3.y); a1[6]=(short)f2b(f3.z); a1[7]=(short)f2b(f3.w);
  } else {
    const ushort* Ab = (const ushort*)Av;
    a0 = *(const bf16x8*)&Ab[(size_t)arow*64 + kg*8];
    a1 = *(const bf16x8*)&Ab[(size_t)arow*64 + 32 + kg*8];
  }
  f32x4 acc[8];
  #pragma unroll
  for (int t=0; t<8; t++){
    bf16x8 b0 = *(const bf16x8*)&wp[((size_t)(0*8+t)*64 + l)*8];
    bf16x8 b1 = *(const bf16x8*)&wp[((size_t)(1*8+t)*64 + l)*8];
    f32x4 c = {0.f, 0.f, 0.f, 0.f};
    c = __builtin_amdgcn_mfma_f32_16x16x32_bf16(a0, b0, c, 0, 0, 0);
    c = __builtin_amdgcn_mfma_f32_16x16x32_bf16(a1, b1, c, 0, 0, 0);
    acc[t] = c;
  }
  #pragma unroll
  for (int t=0; t<8; t++){
    #pragma unroll
    for (int reg=0; reg<4; reg++){
      int row = row0 + kg*4 + reg;       // D: row = (lane>>4)*4 + reg, col = lane&15
      if (row < NN){
        ushort o = f2b(acc[t][reg]);
        if (t < 4) Y [(size_t)row*64 + t*16 + m]     = o;
        else       Rr[(size_t)row*64 + (t-4)*16 + m] = o;
      }
    }
  }
}

// ---------------- gather-aggregate: 8 lanes/edge (ushort8), 16 edges in flight ----------------
__global__ __launch_bounds__(256) void k_aggr(const ushort* __restrict__ Y,
    const ushort* __restrict__ R, const float* __restrict__ brel,
    const int* __restrict__ rowptr, const int* __restrict__ degarr, const int* __restrict__ csr,
    ushort* __restrict__ hout, int do_relu){
  int node = blockIdx.x*4 + (threadIdx.x>>6);
  if (node >= NN) return;
  int lane = threadIdx.x & 63;
  int g = lane >> 3;
  int c8 = (lane & 7) << 3;
  int beg = rowptr[node];
  int dc = degarr[node];
  const int* lst = csr + beg;
  float a[8] = {0.f,0.f,0.f,0.f,0.f,0.f,0.f,0.f};
  int i = g;
  for (; i + 8 < dc; i += 16){          // pair: 16 edges in flight per wave
    int s0 = lst[i], s1 = lst[i+8];
    ushort8v y0 = *(const ushort8v*)&Y[((size_t)s0<<6) + c8];
    ushort8v y1 = *(const ushort8v*)&Y[((size_t)s1<<6) + c8];
    #pragma unroll
    for (int j=0;j<8;j++) a[j] += b2f(y0[j]) + b2f(y1[j]);
  }
  if (i < dc){
    int s0 = lst[i];
    ushort8v y0 = *(const ushort8v*)&Y[((size_t)s0<<6) + c8];
    #pragma unroll
    for (int j=0;j<8;j++) a[j] += b2f(y0[j]);
  }
  #pragma unroll
  for (int j=0;j<8;j++){
    a[j] += __shfl_xor(a[j], 8);
    a[j] += __shfl_xor(a[j], 16);
    a[j] += __shfl_xor(a[j], 32);
  }
  if (g == 0){
    ushort8v r8 = *(const ushort8v*)&R[((size_t)node<<6) + c8];
    float4 b0 = *(const float4*)&brel[c8];
    float4 b1 = *(const float4*)&brel[c8+4];
    float bb[8] = {b0.x,b0.y,b0.z,b0.w,b1.x,b1.y,b1.z,b1.w};
    ushort8v o;
    #pragma unroll
    for (int j=0;j<8;j++){
      float v = a[j] + b2f(r8[j]) + bb[j];
      if (do_relu) v = fmaxf(v, 0.f);
      o[j] = f2b(v);
    }
    *(ushort8v*)&hout[((size_t)node<<6) + c8] = o;
  }
}

// ---------------- pooling + final linear fused ----------------
__global__ __launch_bounds__(256) void k_pool(const ushort* __restrict__ h, const int* __restrict__ batch,
                       const float* __restrict__ Wlin, const float* __restrict__ blin,
                       float* __restrict__ out){
  int g = blockIdx.x;
  int lo=0, hi=NN;
  while (lo<hi){ int mid=(lo+hi)>>1; if (batch[mid] < g) lo=mid+1; else hi=mid; }
  int beg = lo;
  lo=0; hi=NN;
  while (lo<hi){ int mid=(lo+hi)>>1; if (batch[mid] < g+1) lo=mid+1; else hi=mid; }
  int end = lo;
  int lane = threadIdx.x & 63;
  int w = threadIdx.x >> 6;
  float acc = 0.f;
  for (int n = beg + w; n < end; n += 4) acc += b2f(h[(size_t)n*64 + lane]);
  __shared__ float red[4][64];
  __shared__ float p[64];
  red[w][lane] = acc;
  __syncthreads();
  if (w == 0){
    float v = red[0][lane]+red[1][lane]+red[2][lane]+red[3][lane];
    int cnt = end - beg;
    p[lane] = v / fmaxf((float)cnt, 1.f);
  }
  __syncthreads();
  if (w == 0){
    float o = blin[lane];
    #pragma unroll 8
    for (int k=0;k<64;k++) o += p[k]*Wlin[k*64+lane];
    out[g*64+lane] = o;
  }
}

extern "C" void kernel_launch(void* const* d_in, const int* in_sizes, int n_in,
                              void* d_out, int out_size, void* d_ws, size_t ws_size,
                              hipStream_t stream){
  const float* x     = (const float*)d_in[0];
  const int*   ei    = (const int*)  d_in[1];
  const int*   batch = (const int*)  d_in[2];
  const float* Wrel1 = (const float*)d_in[3];
  const float* brel1 = (const float*)d_in[4];
  const float* Wroot1= (const float*)d_in[5];
  const float* Wrel2 = (const float*)d_in[6];
  const float* brel2 = (const float*)d_in[7];
  const float* Wroot2= (const float*)d_in[8];
  const float* Wrel3 = (const float*)d_in[9];
  const float* brel3 = (const float*)d_in[10];
  const float* Wroot3= (const float*)d_in[11];
  const float* Wlin  = (const float*)d_in[12];
  const float* blin  = (const float*)d_in[13];
  const int* src = ei;
  const int* dst = ei + NE;

  char* wsB = (char*)d_ws;
  size_t off = 0;
  auto alloc = [&](size_t bytes)->void*{
    void* p = wsB + off; off = (off + bytes + 255) & ~(size_t)255; return p;
  };
  int*      csr    = (int*)     alloc((size_t)NBK*BCAP*4);    // 7.2 MB bucket-padded
  unsigned* ebuf   = (unsigned*)alloc((size_t)NBK*BCAP*4);    // 7.2 MB bucket-padded
  int*      rowptr = (int*)     alloc((size_t)NN*4);
  int*      degarr = (int*)     alloc((size_t)NN*4);
  int*      gcur   = (int*)     alloc(NBK*4);
  ushort*   wp     = (ushort*)  alloc((size_t)3*8192*2);      // 48 KB
  ushort*   Y      = (ushort*)  alloc((size_t)NN*64*2);       // 12.8 MB
  ushort*   R      = (ushort*)  alloc((size_t)NN*64*2);       // 12.8 MB
  ushort*   h1     = (ushort*)  alloc((size_t)NN*64*2);       // 12.8 MB
  ushort*   h2     = (ushort*)  alloc((size_t)NN*64*2);       // 12.8 MB

  k_wpack3  <<<(3*8192+255)/256,256,0,stream>>>(Wrel1,Wroot1,Wrel2,Wroot2,Wrel3,Wroot3, wp, gcur);
  k_bscatter<<<NSB,256,0,stream>>>(src, dst, gcur, ebuf);
  k_bfill   <<<NBK,256,0,stream>>>(ebuf, gcur, rowptr, degarr, csr);

  int gb = (NN+63)/64;
  int ab = (NN+3)/4;

  // layer 1 (A = x, f32, cast fused into GEMM)
  k_gemm_mfma<<<gb,256,0,stream>>>(x,  1, wp + 0*8192, Y, R);
  k_aggr     <<<ab,256,0,stream>>>(Y, R, brel1, rowptr, degarr, csr, h1, 1);
  // layer 2
  k_gemm_mfma<<<gb,256,0,stream>>>(h1, 0, wp + 1*8192, Y, R);
  k_aggr     <<<ab,256,0,stream>>>(Y, R, brel2, rowptr, degarr, csr, h2, 1);
  // layer 3 (no relu)
  k_gemm_mfma<<<gb,256,0,stream>>>(h2, 0, wp + 2*8192, Y, R);
  k_aggr     <<<ab,256,0,stream>>>(Y, R, brel3, rowptr, degarr, csr, h1, 0);

  k_pool <<<NG,256,0,stream>>>(h1, batch, Wlin, blin, (float*)d_out);
}

// Round 14
// 251.895 us; speedup vs baseline: 7.7742x; 1.0196x over previous
//
#include <hip/hip_runtime.h>
#include <hip/hip_bf16.h>

#define NN 100000
#define NE 1600000
#define DD 64
#define NG 256
#define SHIFT 8     // 256 nodes per bucket
#define NBK 391     // ceil(NN/256)
#define BCAP 4608   // bucket capacity: mean 4092, +8 sigma
#define NSB 256     // scatter blocks
#define CHUNK 6250  // edges per scatter block

typedef __attribute__((ext_vector_type(8))) short bf16x8;
typedef __attribute__((ext_vector_type(4))) float f32x4;
typedef __attribute__((ext_vector_type(8))) unsigned short ushort8v;

__device__ __forceinline__ float b2f(ushort u){
  unsigned v = ((unsigned)u) << 16;
  return __uint_as_float(v);
}
__device__ __forceinline__ ushort f2b(float f){
  __hip_bfloat16 b = __float2bfloat16(f);
  return *(ushort*)&b;
}

// ---------------- weight packing + gcur init (fused) ----------------
// wp layout per layer: [s(2)][t(8)][lane(64)][j(8)] bf16
// value = W[k][col], k = s*32 + (lane>>4)*8 + j, col = t*16 + (lane&15)
__global__ void k_wpack3(const float* __restrict__ Wr1, const float* __restrict__ Wo1,
                         const float* __restrict__ Wr2, const float* __restrict__ Wo2,
                         const float* __restrict__ Wr3, const float* __restrict__ Wo3,
                         ushort* __restrict__ wp, int* __restrict__ gcur){
  int i = blockIdx.x*256 + threadIdx.x;
  if (i < NBK) gcur[i] = i*BCAP;          // fixed bucket bases
  if (i >= 3*8192) return;
  int lay = i >> 13;
  int r = i & 8191;
  int j = r & 7, l = (r>>3) & 63, t = (r>>9) & 7, s = r >> 12;
  int k = s*32 + ((l>>4)<<3) + j;
  int col = t*16 + (l&15);
  const float* Wrel  = (lay==0) ? Wr1 : (lay==1) ? Wr2 : Wr3;
  const float* Wroot = (lay==0) ? Wo1 : (lay==1) ? Wo2 : Wo3;
  float v = (col < 64) ? Wrel[k*64 + col] : Wroot[k*64 + (col-64)];
  wp[i] = f2b(v);
}

// ---------------- scatter: per-block hist -> reserve -> write packed edges ----------------
__global__ __launch_bounds__(256) void k_bscatter(const int* __restrict__ src, const int* __restrict__ dst,
                           int* __restrict__ gcur, unsigned* __restrict__ ebuf){
  __shared__ int h[NBK];
  __shared__ int base[NBK];
  __shared__ int lcur[NBK];
  for (int i=threadIdx.x; i<NBK; i+=256) h[i]=0;
  __syncthreads();
  const int e0 = blockIdx.x*CHUNK;
  const int e1 = min(e0+CHUNK, NE);
  for (int e=e0+threadIdx.x; e<e1; e+=256) atomicAdd(&h[dst[e]>>SHIFT], 1);
  __syncthreads();
  for (int i=threadIdx.x; i<NBK; i+=256){
    base[i] = h[i] ? atomicAdd(&gcur[i], h[i]) : 0;
    lcur[i] = 0;
  }
  __syncthreads();
  for (int e=e0+threadIdx.x; e<e1; e+=256){
    int d = dst[e];
    int b = d >> SHIFT;
    int r = atomicAdd(&lcur[b], 1);
    size_t idx = (size_t)base[b] + r;
    if (idx < (size_t)NBK*BCAP)
      ebuf[idx] = ((unsigned)(d & 255) << 17) | (unsigned)src[e];   // 8b local-dst | 17b src
  }
}

// ---------------- per-bucket LDS counting sort -> bucket-padded CSR + rowptr + deg ----------------
__global__ __launch_bounds__(256) void k_bfill(const unsigned* __restrict__ ebuf, const int* __restrict__ gcur,
                        int* __restrict__ rowptr, int* __restrict__ degarr, int* __restrict__ csr){
  __shared__ int c[256];
  __shared__ int lcur[256];
  __shared__ int s[256];
  __shared__ int scnt;
  const int b = blockIdx.x, t = threadIdx.x;
  const int ebase = b*BCAP;
  if (t == 0) scnt = min(gcur[b] - ebase, BCAP);
  c[t] = 0;
  __syncthreads();
  const int cnt = scnt;
  for (int i=t; i<cnt; i+=256) atomicAdd(&c[ebuf[ebase+i]>>17], 1);
  __syncthreads();
  int v = c[t];
  s[t] = v;
  __syncthreads();
  for (int off=1; off<256; off<<=1){
    int u = (t >= off) ? s[t-off] : 0;
    __syncthreads();
    s[t] += u;
    __syncthreads();
  }
  int excl = s[t] - v;
  lcur[t] = excl;
  int node = (b << SHIFT) + t;
  if (node < NN){ rowptr[node] = ebase + excl; degarr[node] = v; }
  __syncthreads();
  for (int i=t; i<cnt; i+=256){
    unsigned p = ebuf[ebase+i];
    int dl = (int)(p >> 17);
    int r = atomicAdd(&lcur[dl], 1);
    csr[ebase + r] = (int)(p & 0x1FFFFu);
  }
}

// ---------------- MFMA dual GEMM: [Y | R] = A @ [Wrel | Wroot] ----------------
// LDS-transpose epilogue: C tile staged in LDS, re-read as ushort8 -> coalesced 16B stores.
#define CPAD 136   // row pad (ushorts): 272B = 16B-aligned rows, bank-spread
__global__ __launch_bounds__(256) void k_gemm_mfma(const void* __restrict__ Av, int aIsF32,
    const ushort* __restrict__ wp, ushort* __restrict__ Y, ushort* __restrict__ Rr){
  __shared__ ushort ct[64*CPAD];   // 17408 B
  const int tid = threadIdx.x;
  const int w = tid >> 6, l = tid & 63;
  const int m = l & 15, kg = l >> 4;
  const int row0 = blockIdx.x*64;
  int arow = row0 + w*16 + m; if (arow >= NN) arow = NN-1;   // clamp; stores guarded
  bf16x8 a0, a1;
  if (aIsF32){
    const float* Af = (const float*)Av;
    float4 f0 = *(const float4*)&Af[(size_t)arow*64 + kg*8];
    float4 f1 = *(const float4*)&Af[(size_t)arow*64 + kg*8 + 4];
    float4 f2 = *(const float4*)&Af[(size_t)arow*64 + 32 + kg*8];
    float4 f3 = *(const float4*)&Af[(size_t)arow*64 + 32 + kg*8 + 4];
    a0[0]=(short)f2b(f0.x); a0[1]=(short)f2b(f0.y); a0[2]=(short)f2b(f0.z); a0[3]=(short)f2b(f0.w);
    a0[4]=(short)f2b(f1.x); a0[5]=(short)f2b(f1.y); a0[6]=(short)f2b(f1.z); a0[7]=(short)f2b(f1.w);
    a1[0]=(short)f2b(f2.x); a1[1]=(short)f2b(f2.y); a1[2]=(short)f2b(f2.z); a1[3]=(short)f2b(f2.w);
    a1[4]=(short)f2b(f3.x); a1[5]=(short)f2b(f3.y); a1[6]=(short)f2b(f3.z); a1[7]=(short)f2b(f3.w);
  } else {
    const ushort* Ab = (const ushort*)Av;
    a0 = *(const bf16x8*)&Ab[(size_t)arow*64 + kg*8];
    a1 = *(const bf16x8*)&Ab[(size_t)arow*64 + 32 + kg*8];
  }
  #pragma unroll
  for (int t=0; t<8; t++){
    bf16x8 b0 = *(const bf16x8*)&wp[((size_t)(0*8+t)*64 + l)*8];
    bf16x8 b1 = *(const bf16x8*)&wp[((size_t)(1*8+t)*64 + l)*8];
    f32x4 c = {0.f, 0.f, 0.f, 0.f};
    c = __builtin_amdgcn_mfma_f32_16x16x32_bf16(a0, b0, c, 0, 0, 0);
    c = __builtin_amdgcn_mfma_f32_16x16x32_bf16(a1, b1, c, 0, 0, 0);
    #pragma unroll
    for (int reg=0; reg<4; reg++){
      int lrow = w*16 + kg*4 + reg;     // D: row=(lane>>4)*4+reg, col=lane&15
      ct[lrow*CPAD + t*16 + m] = f2b(c[reg]);
    }
  }
  __syncthreads();
  // cooperative coalesced store: 64 rows x 16 col-blocks of 8 ushorts
  #pragma unroll
  for (int u=0; u<4; u++){
    int i = tid + u*256;               // 0..1023
    int lrow = i >> 4, cb = i & 15;
    int grow = row0 + lrow;
    if (grow < NN){
      ushort8v v = *(const ushort8v*)&ct[lrow*CPAD + cb*8];
      if (cb < 8) *(ushort8v*)&Y [(size_t)grow*64 + cb*8]       = v;
      else        *(ushort8v*)&Rr[(size_t)grow*64 + (cb-8)*8]   = v;
    }
  }
}

// ---------------- gather-aggregate: 8 lanes/edge (ushort8), 16 edges in flight ----------------
__global__ __launch_bounds__(256) void k_aggr(const ushort* __restrict__ Y,
    const ushort* __restrict__ R, const float* __restrict__ brel,
    const int* __restrict__ rowptr, const int* __restrict__ degarr, const int* __restrict__ csr,
    ushort* __restrict__ hout, int do_relu){
  int node = blockIdx.x*4 + (threadIdx.x>>6);
  if (node >= NN) return;
  int lane = threadIdx.x & 63;
  int g = lane >> 3;
  int c8 = (lane & 7) << 3;
  int beg = rowptr[node];
  int dc = degarr[node];
  const int* lst = csr + beg;
  float a[8] = {0.f,0.f,0.f,0.f,0.f,0.f,0.f,0.f};
  int i = g;
  for (; i + 8 < dc; i += 16){          // pair: 16 edges in flight per wave
    int s0 = lst[i], s1 = lst[i+8];
    ushort8v y0 = *(const ushort8v*)&Y[((size_t)s0<<6) + c8];
    ushort8v y1 = *(const ushort8v*)&Y[((size_t)s1<<6) + c8];
    #pragma unroll
    for (int j=0;j<8;j++) a[j] += b2f(y0[j]) + b2f(y1[j]);
  }
  if (i < dc){
    int s0 = lst[i];
    ushort8v y0 = *(const ushort8v*)&Y[((size_t)s0<<6) + c8];
    #pragma unroll
    for (int j=0;j<8;j++) a[j] += b2f(y0[j]);
  }
  #pragma unroll
  for (int j=0;j<8;j++){
    a[j] += __shfl_xor(a[j], 8);
    a[j] += __shfl_xor(a[j], 16);
    a[j] += __shfl_xor(a[j], 32);
  }
  if (g == 0){
    ushort8v r8 = *(const ushort8v*)&R[((size_t)node<<6) + c8];
    float4 b0 = *(const float4*)&brel[c8];
    float4 b1 = *(const float4*)&brel[c8+4];
    float bb[8] = {b0.x,b0.y,b0.z,b0.w,b1.x,b1.y,b1.z,b1.w};
    ushort8v o;
    #pragma unroll
    for (int j=0;j<8;j++){
      float v = a[j] + b2f(r8[j]) + bb[j];
      if (do_relu) v = fmaxf(v, 0.f);
      o[j] = f2b(v);
    }
    *(ushort8v*)&hout[((size_t)node<<6) + c8] = o;
  }
}

// ---------------- pooling + final linear fused ----------------
__global__ __launch_bounds__(256) void k_pool(const ushort* __restrict__ h, const int* __restrict__ batch,
                       const float* __restrict__ Wlin, const float* __restrict__ blin,
                       float* __restrict__ out){
  int g = blockIdx.x;
  int lo=0, hi=NN;
  while (lo<hi){ int mid=(lo+hi)>>1; if (batch[mid] < g) lo=mid+1; else hi=mid; }
  int beg = lo;
  lo=0; hi=NN;
  while (lo<hi){ int mid=(lo+hi)>>1; if (batch[mid] < g+1) lo=mid+1; else hi=mid; }
  int end = lo;
  int lane = threadIdx.x & 63;
  int w = threadIdx.x >> 6;
  float acc = 0.f;
  for (int n = beg + w; n < end; n += 4) acc += b2f(h[(size_t)n*64 + lane]);
  __shared__ float red[4][64];
  __shared__ float p[64];
  red[w][lane] = acc;
  __syncthreads();
  if (w == 0){
    float v = red[0][lane]+red[1][lane]+red[2][lane]+red[3][lane];
    int cnt = end - beg;
    p[lane] = v / fmaxf((float)cnt, 1.f);
  }
  __syncthreads();
  if (w == 0){
    float o = blin[lane];
    #pragma unroll 8
    for (int k=0;k<64;k++) o += p[k]*Wlin[k*64+lane];
    out[g*64+lane] = o;
  }
}

extern "C" void kernel_launch(void* const* d_in, const int* in_sizes, int n_in,
                              void* d_out, int out_size, void* d_ws, size_t ws_size,
                              hipStream_t stream){
  const float* x     = (const float*)d_in[0];
  const int*   ei    = (const int*)  d_in[1];
  const int*   batch = (const int*)  d_in[2];
  const float* Wrel1 = (const float*)d_in[3];
  const float* brel1 = (const float*)d_in[4];
  const float* Wroot1= (const float*)d_in[5];
  const float* Wrel2 = (const float*)d_in[6];
  const float* brel2 = (const float*)d_in[7];
  const float* Wroot2= (const float*)d_in[8];
  const float* Wrel3 = (const float*)d_in[9];
  const float* brel3 = (const float*)d_in[10];
  const float* Wroot3= (const float*)d_in[11];
  const float* Wlin  = (const float*)d_in[12];
  const float* blin  = (const float*)d_in[13];
  const int* src = ei;
  const int* dst = ei + NE;

  char* wsB = (char*)d_ws;
  size_t off = 0;
  auto alloc = [&](size_t bytes)->void*{
    void* p = wsB + off; off = (off + bytes + 255) & ~(size_t)255; return p;
  };
  int*      csr    = (int*)     alloc((size_t)NBK*BCAP*4);    // 7.2 MB bucket-padded
  unsigned* ebuf   = (unsigned*)alloc((size_t)NBK*BCAP*4);    // 7.2 MB bucket-padded
  int*      rowptr = (int*)     alloc((size_t)NN*4);
  int*      degarr = (int*)     alloc((size_t)NN*4);
  int*      gcur   = (int*)     alloc(NBK*4);
  ushort*   wp     = (ushort*)  alloc((size_t)3*8192*2);      // 48 KB
  ushort*   Y      = (ushort*)  alloc((size_t)NN*64*2);       // 12.8 MB
  ushort*   R      = (ushort*)  alloc((size_t)NN*64*2);       // 12.8 MB
  ushort*   h1     = (ushort*)  alloc((size_t)NN*64*2);       // 12.8 MB
  ushort*   h2     = (ushort*)  alloc((size_t)NN*64*2);       // 12.8 MB

  k_wpack3  <<<(3*8192+255)/256,256,0,stream>>>(Wrel1,Wroot1,Wrel2,Wroot2,Wrel3,Wroot3, wp, gcur);
  k_bscatter<<<NSB,256,0,stream>>>(src, dst, gcur, ebuf);
  k_bfill   <<<NBK,256,0,stream>>>(ebuf, gcur, rowptr, degarr, csr);

  int gb = (NN+63)/64;
  int ab = (NN+3)/4;

  // layer 1 (A = x, f32, cast fused into GEMM)
  k_gemm_mfma<<<gb,256,0,stream>>>(x,  1, wp + 0*8192, Y, R);
  k_aggr     <<<ab,256,0,stream>>>(Y, R, brel1, rowptr, degarr, csr, h1, 1);
  // layer 2
  k_gemm_mfma<<<gb,256,0,stream>>>(h1, 0, wp + 1*8192, Y, R);
  k_aggr     <<<ab,256,0,stream>>>(Y, R, brel2, rowptr, degarr, csr, h2, 1);
  // layer 3 (no relu)
  k_gemm_mfma<<<gb,256,0,stream>>>(h2, 0, wp + 2*8192, Y, R);
  k_aggr     <<<ab,256,0,stream>>>(Y, R, brel3, rowptr, degarr, csr, h1, 0);

  k_pool <<<NG,256,0,stream>>>(h1, batch, Wlin, blin, (float*)d_out);
}